// Round 1
// baseline (1904.481 us; speedup 1.0000x reference)
//
#include <hip/hip_runtime.h>
#include <math.h>

// Problem constants
#define B_   16
#define N_   1024
#define H_   4
#define D240 240

// ---------------------------------------------------------------------------
// heads permute: emb_all [B,N,960] -> heads [B,H,N,240]
// head h gets: [16h:16h+16) of ch 0..64, [64+32h:..+32), [192+64h:..+64), [448+128h:..+128)
// ---------------------------------------------------------------------------
__global__ __launch_bounds__(256) void make_heads(const float* __restrict__ emb_all,
                                                  float* __restrict__ heads) {
  const int bn = blockIdx.x;            // b*N + n
  const int b = bn >> 10;               // / 1024
  const int n = bn & 1023;
  const float* src = emb_all + (long)bn * 960;
  for (int c = threadIdx.x; c < 960; c += 256) {
    int h, dl;
    if (c < 64)       { h = c >> 4;            dl = (c & 15); }
    else if (c < 192) { int t = c - 64;  h = t >> 5; dl = 16  + (t & 31); }
    else if (c < 448) { int t = c - 192; h = t >> 6; dl = 48  + (t & 63); }
    else              { int t = c - 448; h = t >> 7; dl = 112 + (t & 127); }
    heads[(((long)b * H_ + h) * N_ + n) * D240 + dl] = src[c];
  }
}

// ---------------------------------------------------------------------------
// Generic tiled GEMM #1:  C[m,n] = alpha * sum_k A[m,k] * B[n,k]   (A·B^T)
// A row-major [M x K] (lda), B row-major [Nn x K] (ldb).
// C addressed as C[m*csm + n*csn]. Batch over grid.y / grid.z with strides.
// Tiles: 64x64, k-chunk 16, 256 threads, 4x4 micro-tile. K must be mult of 16.
// ---------------------------------------------------------------------------
__global__ __launch_bounds__(256) void gemm_abT(
    const float* __restrict__ A, int lda, long AsY, long AsZ,
    const float* __restrict__ Bm, int ldb, long BsY, long BsZ,
    float* __restrict__ C, int csm, int csn, long CsY, long CsZ,
    int M, int Nn, int K, float alpha, int tilesN)
{
  A  += (long)blockIdx.y * AsY + (long)blockIdx.z * AsZ;
  Bm += (long)blockIdx.y * BsY + (long)blockIdx.z * BsZ;
  C  += (long)blockIdx.y * CsY + (long)blockIdx.z * CsZ;

  const int tm = blockIdx.x / tilesN, tn = blockIdx.x % tilesN;
  const int m0 = tm * 64, n0 = tn * 64;
  const int tid = threadIdx.x;

  __shared__ float As[16][68];   // [k][m], pad->row stride 68 (16B aligned, 2-way bank max)
  __shared__ float Bs[16][68];   // [k][n]

  float acc[4][4] = {{0.f}};

  const int lk = tid & 15;       // k within chunk (contiguous dim -> coalesced-ish)
  const int lm = tid >> 4;       // 0..15

  for (int k0 = 0; k0 < K; k0 += 16) {
    #pragma unroll
    for (int it = 0; it < 4; ++it) {
      int m = lm + it * 16;
      int gm = m0 + m;
      As[lk][m] = (gm < M)  ? A[(long)gm * lda + k0 + lk]  : 0.f;
      int gn = n0 + m;
      Bs[lk][m] = (gn < Nn) ? Bm[(long)gn * ldb + k0 + lk] : 0.f;
    }
    __syncthreads();
    const int ty = tid >> 4, tx = tid & 15;
    #pragma unroll
    for (int kk = 0; kk < 16; ++kk) {
      float4 a = *(const float4*)&As[kk][ty * 4];
      float4 b = *(const float4*)&Bs[kk][tx * 4];
      float av[4] = {a.x, a.y, a.z, a.w};
      float bv[4] = {b.x, b.y, b.z, b.w};
      #pragma unroll
      for (int i = 0; i < 4; ++i)
        #pragma unroll
        for (int j = 0; j < 4; ++j) acc[i][j] += av[i] * bv[j];
    }
    __syncthreads();
  }

  const int ty = tid >> 4, tx = tid & 15;
  #pragma unroll
  for (int i = 0; i < 4; ++i) {
    int m = m0 + ty * 4 + i;
    if (m >= M) continue;
    #pragma unroll
    for (int j = 0; j < 4; ++j) {
      int n = n0 + tx * 4 + j;
      if (n < Nn) C[(long)m * csm + (long)n * csn] = alpha * acc[i][j];
    }
  }
}

// ---------------------------------------------------------------------------
// Generic tiled GEMM #2:  C[m,n] = alpha * sum_k A[k,m] * B[k,n]   (A^T·B)
// A row-major [K x M] (lda), B row-major [K x Nn] (ldb). Same tiling.
// ---------------------------------------------------------------------------
__global__ __launch_bounds__(256) void gemm_aTb(
    const float* __restrict__ A, int lda, long AsY, long AsZ,
    const float* __restrict__ Bm, int ldb, long BsY, long BsZ,
    float* __restrict__ C, int csm, int csn, long CsY, long CsZ,
    int M, int Nn, int K, float alpha, int tilesN)
{
  A  += (long)blockIdx.y * AsY + (long)blockIdx.z * AsZ;
  Bm += (long)blockIdx.y * BsY + (long)blockIdx.z * BsZ;
  C  += (long)blockIdx.y * CsY + (long)blockIdx.z * CsZ;

  const int tm = blockIdx.x / tilesN, tn = blockIdx.x % tilesN;
  const int m0 = tm * 64, n0 = tn * 64;
  const int tid = threadIdx.x;

  __shared__ float As[16][68];
  __shared__ float Bs[16][68];

  float acc[4][4] = {{0.f}};

  const int lm = tid & 63;       // col within tile (contiguous dim -> fully coalesced)
  const int lk = tid >> 6;       // 0..3

  for (int k0 = 0; k0 < K; k0 += 16) {
    #pragma unroll
    for (int it = 0; it < 4; ++it) {
      int kk = lk * 4 + it;
      long krowA = (long)(k0 + kk) * lda;
      long krowB = (long)(k0 + kk) * ldb;
      As[kk][lm] = (m0 + lm < M)  ? A[krowA + m0 + lm]  : 0.f;
      Bs[kk][lm] = (n0 + lm < Nn) ? Bm[krowB + n0 + lm] : 0.f;
    }
    __syncthreads();
    const int ty = tid >> 4, tx = tid & 15;
    #pragma unroll
    for (int kk = 0; kk < 16; ++kk) {
      float4 a = *(const float4*)&As[kk][ty * 4];
      float4 b = *(const float4*)&Bs[kk][tx * 4];
      float av[4] = {a.x, a.y, a.z, a.w};
      float bv[4] = {b.x, b.y, b.z, b.w};
      #pragma unroll
      for (int i = 0; i < 4; ++i)
        #pragma unroll
        for (int j = 0; j < 4; ++j) acc[i][j] += av[i] * bv[j];
    }
    __syncthreads();
  }

  const int ty = tid >> 4, tx = tid & 15;
  #pragma unroll
  for (int i = 0; i < 4; ++i) {
    int m = m0 + ty * 4 + i;
    if (m >= M) continue;
    #pragma unroll
    for (int j = 0; j < 4; ++j) {
      int n = n0 + tx * 4 + j;
      if (n < Nn) C[(long)m * csm + (long)n * csn] = alpha * acc[i][j];
    }
  }
}

// ---------------------------------------------------------------------------
// InstanceNorm (per (b,h) over d*240, biased var, eps=1e-5) + row softmax (240)
// In-place on sc [B*H, d, 240]. One block per (b,h), 4 waves, one wave per row.
// ---------------------------------------------------------------------------
__global__ __launch_bounds__(256) void inorm_softmax(float* __restrict__ sc, int d) {
  float* S = sc + (long)blockIdx.x * d * D240;
  const int n = d * D240;

  float s = 0.f, s2 = 0.f;
  for (int i = threadIdx.x; i < n; i += 256) { float v = S[i]; s += v; s2 += v * v; }
  #pragma unroll
  for (int o = 32; o > 0; o >>= 1) { s += __shfl_down(s, o); s2 += __shfl_down(s2, o); }

  __shared__ float wsum[4], wsum2[4];
  __shared__ float stat[2];
  const int wave = threadIdx.x >> 6, lane = threadIdx.x & 63;
  if (lane == 0) { wsum[wave] = s; wsum2[wave] = s2; }
  __syncthreads();
  if (threadIdx.x == 0) {
    float ts = wsum[0] + wsum[1] + wsum[2] + wsum[3];
    float ts2 = wsum2[0] + wsum2[1] + wsum2[2] + wsum2[3];
    float mean = ts / (float)n;
    float var = ts2 / (float)n - mean * mean;
    stat[0] = mean;
    stat[1] = rsqrtf(var + 1e-5f);
  }
  __syncthreads();
  const float mean = stat[0], rstd = stat[1];

  for (int r = wave; r < d; r += 4) {
    float* row = S + (long)r * D240;
    float v[4];
    float mx = -1e30f;
    #pragma unroll
    for (int j = 0; j < 4; ++j) {
      int c = lane + j * 64;
      v[j] = (c < D240) ? (row[c] - mean) * rstd : -1e30f;
      mx = fmaxf(mx, v[j]);
    }
    #pragma unroll
    for (int o = 32; o > 0; o >>= 1) mx = fmaxf(mx, __shfl_xor(mx, o));
    float sum = 0.f;
    #pragma unroll
    for (int j = 0; j < 4; ++j) {
      int c = lane + j * 64;
      v[j] = (c < D240) ? __expf(v[j] - mx) : 0.f;
      sum += v[j];
    }
    #pragma unroll
    for (int o = 32; o > 0; o >>= 1) sum += __shfl_xor(sum, o);
    float inv = 1.f / sum;
    #pragma unroll
    for (int j = 0; j < 4; ++j) {
      int c = lane + j * 64;
      if (c < D240) row[c] = v[j] * inv;
    }
  }
}

// ---------------------------------------------------------------------------
// launch
// ---------------------------------------------------------------------------
extern "C" void kernel_launch(void* const* d_in, const int* in_sizes, int n_in,
                              void* d_out, int out_size, void* d_ws, size_t ws_size,
                              hipStream_t stream) {
  const float* emb[4] = {(const float*)d_in[0], (const float*)d_in[1],
                         (const float*)d_in[2], (const float*)d_in[3]};
  const float* emb_all = (const float*)d_in[4];
  const float* Wq[4] = {(const float*)d_in[5], (const float*)d_in[6],
                        (const float*)d_in[7], (const float*)d_in[8]};
  const float* Wk = (const float*)d_in[9];
  const float* Wv = (const float*)d_in[10];
  const float* Wo[4] = {(const float*)d_in[11], (const float*)d_in[12],
                        (const float*)d_in[13], (const float*)d_in[14]};
  float* out = (float*)d_out;

  // Workspace (floats). R1 (15,728,640) holds heads, later aliased by Qh/ctx + sc.
  float* ws = (float*)d_ws;
  float* heads = ws;                      // [B,H,N,240]  (dead after K/V proj)
  float* Qh    = ws;                      // [B,H,N,d]    (aliases heads)
  float* ctx   = ws;                      // [B,N,c]      (aliases Qh; Qh dead by then)
  float* sc    = ws + 8388608;            // [B,H,d,240]  max 1,966,080 floats
  float* Kh    = ws + 15728640;           // [B,H,N,240]
  float* Vh    = ws + 31457280;           // [B,H,N,240]
  // total: 47,185,920 floats = 189 MB

  make_heads<<<dim3(B_ * N_), 256, 0, stream>>>(emb_all, heads);

  // K/V projections: per (b,h): [1024x240] @ [240x240]^T
  {
    dim3 g(16 * 4, B_ * H_, 1);
    gemm_abT<<<g, 256, 0, stream>>>(heads, D240, (long)N_ * D240, 0,
                                    Wk, D240, 0, 0,
                                    Kh, D240, 1, (long)N_ * D240, 0,
                                    N_, D240, D240, 1.f, 4);
    gemm_abT<<<g, 256, 0, stream>>>(heads, D240, (long)N_ * D240, 0,
                                    Wv, D240, 0, 0,
                                    Vh, D240, 1, (long)N_ * D240, 0,
                                    N_, D240, D240, 1.f, 4);
  }

  const int CHs[4] = {64, 128, 256, 512};
  const float alpha_s = 1.0f / sqrtf(960.0f);  // keep: eps is applied to scaled variance
  long ooff = 0;
  for (int i = 0; i < 4; ++i) {
    const int c = CHs[i], d = c / 4;
    const int tNd = (d + 63) / 64;  // 1,1,1,2

    // Q projection: Qh[b,h,n,e] = sum_dd emb[b,n,h*d+dd] * Wq[h,e,dd]
    gemm_abT<<<dim3(16 * tNd, H_, B_), 256, 0, stream>>>(
        emb[i], c, (long)d, (long)N_ * c,
        Wq[i], d, (long)d * d, 0,
        Qh, d, 1, (long)N_ * d, (long)H_ * N_ * d,
        N_, d, d, 1.f, tNd);

    // scores: sc[b,h,e,k] = (1/sqrt(960)) * sum_n Qh[b,h,n,e] * Kh[b,h,n,k]
    gemm_aTb<<<dim3(tNd * 4, H_, B_), 256, 0, stream>>>(
        Qh, d, (long)N_ * d, (long)H_ * N_ * d,
        Kh, D240, (long)N_ * D240, (long)H_ * N_ * D240,
        sc, D240, 1, (long)d * D240, (long)H_ * d * D240,
        d, D240, N_, alpha_s, 4);

    // InstanceNorm + softmax (in-place)
    inorm_softmax<<<dim3(B_ * H_), 256, 0, stream>>>(sc, d);

    // ctx: ctx_flat[b, n, dd*H+h] = sum_k Vh[b,h,n,k] * probs[b,h,dd,k]
    gemm_abT<<<dim3(16 * tNd, H_, B_), 256, 0, stream>>>(
        Vh, D240, (long)N_ * D240, (long)H_ * N_ * D240,
        sc, D240, (long)d * D240, (long)H_ * d * D240,
        ctx, c, H_, 1L, (long)N_ * c,
        N_, d, D240, 1.f, tNd);

    // output projection: out[b,n,e] = sum_c' ctx_flat[b,n,c'] * Wo[e,c']
    gemm_abT<<<dim3(256 * (c / 64), 1, 1), 256, 0, stream>>>(
        ctx, c, 0, 0,
        Wo[i], c, 0, 0,
        out + ooff, c, 1, 0, 0,
        B_ * N_, c, c, 1.f, c / 64);

    ooff += (long)B_ * N_ * c;
  }
}

// Round 2
// 1392.333 us; speedup vs baseline: 1.3678x; 1.3678x over previous
//
#include <hip/hip_runtime.h>
#include <math.h>

// Problem constants
#define B_   16
#define N_   1024
#define H_   4
#define D240 240
#define SC_  57600   // 240*240

// ---------------------------------------------------------------------------
// heads permute: emb_all [B,N,960] -> heads [B,H,N,240]
// ---------------------------------------------------------------------------
__global__ __launch_bounds__(256) void make_heads(const float* __restrict__ emb_all,
                                                  float* __restrict__ heads) {
  const int bn = blockIdx.x;            // b*N + n
  const int b = bn >> 10;
  const int n = bn & 1023;
  const float* src = emb_all + (long)bn * 960;
  for (int c = threadIdx.x; c < 960; c += 256) {
    int h, dl;
    if (c < 64)       { h = c >> 4;            dl = (c & 15); }
    else if (c < 192) { int t = c - 64;  h = t >> 5; dl = 16  + (t & 31); }
    else if (c < 448) { int t = c - 192; h = t >> 6; dl = 48  + (t & 63); }
    else              { int t = c - 448; h = t >> 7; dl = 112 + (t & 127); }
    heads[(((long)b * H_ + h) * N_ + n) * D240 + dl] = src[c];
  }
}

// ---------------------------------------------------------------------------
// GEMM #1:  C[m,n] = alpha * sum_k A[m,k] * B[n,k]   (A·B^T)
// 64x64 tile, k-chunk 16, 256 threads, 4x4 micro-tile. K mult of 16.
// ---------------------------------------------------------------------------
__global__ __launch_bounds__(256) void gemm_abT(
    const float* __restrict__ A, int lda, long AsY, long AsZ,
    const float* __restrict__ Bm, int ldb, long BsY, long BsZ,
    float* __restrict__ C, int csm, int csn, long CsY, long CsZ,
    int M, int Nn, int K, float alpha, int tilesN)
{
  A  += (long)blockIdx.y * AsY + (long)blockIdx.z * AsZ;
  Bm += (long)blockIdx.y * BsY + (long)blockIdx.z * BsZ;
  C  += (long)blockIdx.y * CsY + (long)blockIdx.z * CsZ;

  const int tm = blockIdx.x / tilesN, tn = blockIdx.x % tilesN;
  const int m0 = tm * 64, n0 = tn * 64;
  const int tid = threadIdx.x;

  __shared__ float As[16][68];
  __shared__ float Bs[16][68];

  float acc[4][4] = {{0.f}};

  const int lk = tid & 15;
  const int lm = tid >> 4;

  for (int k0 = 0; k0 < K; k0 += 16) {
    #pragma unroll
    for (int it = 0; it < 4; ++it) {
      int m = lm + it * 16;
      int gm = m0 + m;
      As[lk][m] = (gm < M)  ? A[(long)gm * lda + k0 + lk]  : 0.f;
      int gn = n0 + m;
      Bs[lk][m] = (gn < Nn) ? Bm[(long)gn * ldb + k0 + lk] : 0.f;
    }
    __syncthreads();
    const int ty = tid >> 4, tx = tid & 15;
    #pragma unroll
    for (int kk = 0; kk < 16; ++kk) {
      float4 a = *(const float4*)&As[kk][ty * 4];
      float4 b = *(const float4*)&Bs[kk][tx * 4];
      float av[4] = {a.x, a.y, a.z, a.w};
      float bv[4] = {b.x, b.y, b.z, b.w};
      #pragma unroll
      for (int i = 0; i < 4; ++i)
        #pragma unroll
        for (int j = 0; j < 4; ++j) acc[i][j] += av[i] * bv[j];
    }
    __syncthreads();
  }

  const int ty = tid >> 4, tx = tid & 15;
  #pragma unroll
  for (int i = 0; i < 4; ++i) {
    int m = m0 + ty * 4 + i;
    if (m >= M) continue;
    #pragma unroll
    for (int j = 0; j < 4; ++j) {
      int n = n0 + tx * 4 + j;
      if (n < Nn) C[(long)m * csm + (long)n * csn] = alpha * acc[i][j];
    }
  }
}

// ---------------------------------------------------------------------------
// GEMM #2:  C[m,n] = alpha * sum_k A[k,m] * B[k,n]   (A^T·B)
// ---------------------------------------------------------------------------
__global__ __launch_bounds__(256) void gemm_aTb(
    const float* __restrict__ A, int lda, long AsY, long AsZ,
    const float* __restrict__ Bm, int ldb, long BsY, long BsZ,
    float* __restrict__ C, int csm, int csn, long CsY, long CsZ,
    int M, int Nn, int K, float alpha, int tilesN)
{
  A  += (long)blockIdx.y * AsY + (long)blockIdx.z * AsZ;
  Bm += (long)blockIdx.y * BsY + (long)blockIdx.z * BsZ;
  C  += (long)blockIdx.y * CsY + (long)blockIdx.z * CsZ;

  const int tm = blockIdx.x / tilesN, tn = blockIdx.x % tilesN;
  const int m0 = tm * 64, n0 = tn * 64;
  const int tid = threadIdx.x;

  __shared__ float As[16][68];
  __shared__ float Bs[16][68];

  float acc[4][4] = {{0.f}};

  const int lm = tid & 63;
  const int lk = tid >> 6;

  for (int k0 = 0; k0 < K; k0 += 16) {
    #pragma unroll
    for (int it = 0; it < 4; ++it) {
      int kk = lk * 4 + it;
      long krowA = (long)(k0 + kk) * lda;
      long krowB = (long)(k0 + kk) * ldb;
      As[kk][lm] = (m0 + lm < M)  ? A[krowA + m0 + lm]  : 0.f;
      Bs[kk][lm] = (n0 + lm < Nn) ? Bm[krowB + n0 + lm] : 0.f;
    }
    __syncthreads();
    const int ty = tid >> 4, tx = tid & 15;
    #pragma unroll
    for (int kk = 0; kk < 16; ++kk) {
      float4 a = *(const float4*)&As[kk][ty * 4];
      float4 b = *(const float4*)&Bs[kk][tx * 4];
      float av[4] = {a.x, a.y, a.z, a.w};
      float bv[4] = {b.x, b.y, b.z, b.w};
      #pragma unroll
      for (int i = 0; i < 4; ++i)
        #pragma unroll
        for (int j = 0; j < 4; ++j) acc[i][j] += av[i] * bv[j];
    }
    __syncthreads();
  }

  const int ty = tid >> 4, tx = tid & 15;
  #pragma unroll
  for (int i = 0; i < 4; ++i) {
    int m = m0 + ty * 4 + i;
    if (m >= M) continue;
    #pragma unroll
    for (int j = 0; j < 4; ++j) {
      int n = n0 + tx * 4 + j;
      if (n < Nn) C[(long)m * csm + (long)n * csn] = alpha * acc[i][j];
    }
  }
}

// ---------------------------------------------------------------------------
// InstanceNorm + softmax on a per-(b,h,scale) slice of sc_all [64,240,240].
// blockIdx.x = b*H+h (64), blockIdx.y = scale (4). Slice rows are contiguous.
// ---------------------------------------------------------------------------
__global__ __launch_bounds__(256) void inorm_softmax(float* __restrict__ sc) {
  const int doffs[4] = {0, 16, 48, 112};
  const int dss[4]   = {16, 32, 64, 128};
  const int d = dss[blockIdx.y];
  float* S = sc + (long)blockIdx.x * SC_ + doffs[blockIdx.y] * D240;
  const int n = d * D240;

  float s = 0.f, s2 = 0.f;
  for (int i = threadIdx.x; i < n; i += 256) { float v = S[i]; s += v; s2 += v * v; }
  #pragma unroll
  for (int o = 32; o > 0; o >>= 1) { s += __shfl_down(s, o); s2 += __shfl_down(s2, o); }

  __shared__ float wsum[4], wsum2[4];
  __shared__ float stat[2];
  const int wave = threadIdx.x >> 6, lane = threadIdx.x & 63;
  if (lane == 0) { wsum[wave] = s; wsum2[wave] = s2; }
  __syncthreads();
  if (threadIdx.x == 0) {
    float ts = wsum[0] + wsum[1] + wsum[2] + wsum[3];
    float ts2 = wsum2[0] + wsum2[1] + wsum2[2] + wsum2[3];
    float mean = ts / (float)n;
    float var = ts2 / (float)n - mean * mean;
    stat[0] = mean;
    stat[1] = rsqrtf(var + 1e-5f);
  }
  __syncthreads();
  const float mean = stat[0], rstd = stat[1];

  for (int r = wave; r < d; r += 4) {
    float* row = S + (long)r * D240;
    float v[4];
    float mx = -1e30f;
    #pragma unroll
    for (int j = 0; j < 4; ++j) {
      int c = lane + j * 64;
      v[j] = (c < D240) ? (row[c] - mean) * rstd : -1e30f;
      mx = fmaxf(mx, v[j]);
    }
    #pragma unroll
    for (int o = 32; o > 0; o >>= 1) mx = fmaxf(mx, __shfl_xor(mx, o));
    float sum = 0.f;
    #pragma unroll
    for (int j = 0; j < 4; ++j) {
      int c = lane + j * 64;
      v[j] = (c < D240) ? __expf(v[j] - mx) : 0.f;
      sum += v[j];
    }
    #pragma unroll
    for (int o = 32; o > 0; o >>= 1) sum += __shfl_xor(sum, o);
    float inv = 1.f / sum;
    #pragma unroll
    for (int j = 0; j < 4; ++j) {
      int c = lane + j * 64;
      if (c < D240) row[c] = v[j] * inv;
    }
  }
}

// ---------------------------------------------------------------------------
// launch
// ---------------------------------------------------------------------------
extern "C" void kernel_launch(void* const* d_in, const int* in_sizes, int n_in,
                              void* d_out, int out_size, void* d_ws, size_t ws_size,
                              hipStream_t stream) {
  const float* emb[4] = {(const float*)d_in[0], (const float*)d_in[1],
                         (const float*)d_in[2], (const float*)d_in[3]};
  const float* emb_all = (const float*)d_in[4];
  const float* Wq[4] = {(const float*)d_in[5], (const float*)d_in[6],
                        (const float*)d_in[7], (const float*)d_in[8]};
  const float* Wk = (const float*)d_in[9];
  const float* Wv = (const float*)d_in[10];
  const float* Wo[4] = {(const float*)d_in[11], (const float*)d_in[12],
                        (const float*)d_in[13], (const float*)d_in[14]};
  float* out = (float*)d_out;

  // Workspace (floats), 47,185,920 total = 189 MB (same as verified round 0):
  //  R0 [0, 15.7M):  heads -> Q_all [B,H,N,240] -> ctx_all [B,N,960-split]
  //  R1 [15.7M, 31.5M): Kh
  //  R2 [31.5M, 47.2M): Vh
  //  sc_all [64,240,240] (14.7 MB) lives in d_out (overwritten by out-proj later)
  float* ws = (float*)d_ws;
  float* heads   = ws;
  float* Q_all   = ws;             // aliases heads (heads dead after K/V proj)
  float* ctx_all = ws;             // aliases Q_all (dead after scores)
  float* Kh      = ws + 15728640;
  float* Vh      = ws + 31457280;
  float* sc      = (float*)d_out;  // 3,686,400 floats scratch inside out buffer

  const long sKh_h = (long)N_ * D240;          // h-stride of [B,H,N,240]
  const long sKh_b = (long)H_ * N_ * D240;

  make_heads<<<dim3(B_ * N_), 256, 0, stream>>>(emb_all, heads);

  // K/V projections: per (b,h): [1024x240] @ [240x240]^T
  {
    dim3 g(16 * 4, B_ * H_, 1);
    gemm_abT<<<g, 256, 0, stream>>>(heads, D240, sKh_h, 0,
                                    Wk, D240, 0, 0,
                                    Kh, D240, 1, sKh_h, 0,
                                    N_, D240, D240, 1.f, 4);
    gemm_abT<<<g, 256, 0, stream>>>(heads, D240, sKh_h, 0,
                                    Wv, D240, 0, 0,
                                    Vh, D240, 1, sKh_h, 0,
                                    N_, D240, D240, 1.f, 4);
  }

  const int  CHs[4]    = {64, 128, 256, 512};
  const int  qoff[4]   = {0, 16, 48, 112};            // row offset in the 240 dim
  const long ctxoff[4] = {0, 1048576, 3145728, 7340032};
  const float alpha_s = 1.0f / sqrtf(960.0f);

  // Q projections -> Q_all[b,h,n, qoff+e]  (heads dead now)
  for (int i = 0; i < 4; ++i) {
    const int c = CHs[i], d = c / 4;
    const int tNd = (d + 63) / 64;
    gemm_abT<<<dim3(16 * tNd, H_, B_), 256, 0, stream>>>(
        emb[i], c, (long)d, (long)N_ * c,
        Wq[i], d, (long)d * d, 0,
        Q_all + qoff[i], D240, 1, sKh_h, sKh_b,
        N_, d, d, 1.f, tNd);
  }

  // Fused scores: sc[b,h,r,k] = (1/sqrt(960)) * sum_n Q_all[b,h,n,r] * Kh[b,h,n,k]
  gemm_aTb<<<dim3(16, H_, B_), 256, 0, stream>>>(
      Q_all, D240, sKh_h, sKh_b,
      Kh, D240, sKh_h, sKh_b,
      sc, D240, 1, (long)SC_, (long)H_ * SC_,
      D240, D240, N_, alpha_s, 4);

  // InstanceNorm + softmax per (b,h,scale) slice, in-place
  inorm_softmax<<<dim3(B_ * H_, 4), 256, 0, stream>>>(sc);

  // ctx per scale: ctx_i[b,n, dd*H+h] = sum_k Vh[b,h,n,k] * probs[b,h,qoff+dd,k]
  // (Q_all dead -> R0 becomes ctx_all)
  for (int i = 0; i < 4; ++i) {
    const int c = CHs[i], d = c / 4;
    const int tNd = (d + 63) / 64;
    gemm_abT<<<dim3(16 * tNd, H_, B_), 256, 0, stream>>>(
        Vh, D240, sKh_h, sKh_b,
        sc + (long)qoff[i] * D240, D240, (long)SC_, (long)H_ * SC_,
        ctx_all + ctxoff[i], c, H_, 1L, (long)N_ * c,
        N_, d, D240, 1.f, tNd);
  }

  // out projections (sc scratch no longer needed; safe to overwrite d_out)
  for (int i = 0; i < 4; ++i) {
    const int c = CHs[i];
    gemm_abT<<<dim3(256 * (c / 64), 1, 1), 256, 0, stream>>>(
        ctx_all + ctxoff[i], c, 0, 0,
        Wo[i], c, 0, 0,
        out + ctxoff[i], c, 1, 0, 0,
        B_ * N_, c, c, 1.f, c / 64);
  }
}

// Round 3
// 506.350 us; speedup vs baseline: 3.7612x; 2.7497x over previous
//
#include <hip/hip_runtime.h>
#include <hip/hip_bf16.h>
#include <math.h>

#define B_   16
#define N_   1024
#define H_   4
#define D240 240
#define SC_  57600   // 240*240

typedef unsigned short ushort;
typedef __attribute__((ext_vector_type(8))) short bf16x8;   // 8 bf16 = 4 VGPRs
typedef __attribute__((ext_vector_type(4))) float f32x4;

__device__ __forceinline__ ushort f2b(float v) {
  __hip_bfloat16 h = __float2bfloat16(v);
  return *reinterpret_cast<ushort*>(&h);
}

__device__ __forceinline__ void gload16(const void* g, void* s) {
  __builtin_amdgcn_global_load_lds((const __attribute__((address_space(1))) void*)g,
                                   (__attribute__((address_space(3))) void*)s, 16, 0, 0);
}

// ---------------------------------------------------------------------------
// emb_all [B,N,960] fp32 -> heads_b [B,H,N,256] bf16 (cols 240..255 zero)
// ---------------------------------------------------------------------------
__global__ __launch_bounds__(256) void make_heads_b(const float* __restrict__ emb_all,
                                                    ushort* __restrict__ heads) {
  const int bn = blockIdx.x;
  const int b = bn >> 10, n = bn & 1023;
  const float* src = emb_all + (long)bn * 960;
  for (int c = threadIdx.x; c < 960; c += 256) {
    int h, dl;
    if (c < 64)       { h = c >> 4;            dl = (c & 15); }
    else if (c < 192) { int t = c - 64;  h = t >> 5; dl = 16  + (t & 31); }
    else if (c < 448) { int t = c - 192; h = t >> 6; dl = 48  + (t & 63); }
    else              { int t = c - 448; h = t >> 7; dl = 112 + (t & 127); }
    heads[(((long)b * H_ + h) * N_ + n) * 256 + dl] = f2b(src[c]);
  }
  if (threadIdx.x < 64) {
    int h = threadIdx.x >> 4, dl = 240 + (threadIdx.x & 15);
    heads[(((long)b * H_ + h) * N_ + n) * 256 + dl] = 0;
  }
}

// ---------------------------------------------------------------------------
// emb1..4 fp32 -> emb_b [B,N,1024] bf16: segments [H][dpad] at 0/128/256/512,
// pad cols (dd>=d) zero.
// ---------------------------------------------------------------------------
__global__ __launch_bounds__(256) void conv_emb(const float* __restrict__ e1,
                                                const float* __restrict__ e2,
                                                const float* __restrict__ e3,
                                                const float* __restrict__ e4,
                                                ushort* __restrict__ dst) {
  const int bn = blockIdx.x;
  ushort* drow = dst + (long)bn * 1024;
  for (int t = threadIdx.x; t < 1024; t += 256) {
    const float* src; int loc, d, dpad, c;
    if (t < 128)      { loc = t;       d = 16;  dpad = 32;  src = e1; c = 64;  }
    else if (t < 256) { loc = t - 128; d = 32;  dpad = 32;  src = e2; c = 128; }
    else if (t < 512) { loc = t - 256; d = 64;  dpad = 64;  src = e3; c = 256; }
    else              { loc = t - 512; d = 128; dpad = 128; src = e4; c = 512; }
    int h = loc / dpad, dd = loc % dpad;
    drow[t] = (dd < d) ? f2b(src[(long)bn * c + h * d + dd]) : (ushort)0;
  }
}

// fp32 [R,C] -> bf16 [R,Cpad], pad zero
__global__ __launch_bounds__(256) void conv_pad(const float* __restrict__ src,
                                                ushort* __restrict__ dst,
                                                int R, int C, int Cpad) {
  long i = (long)blockIdx.x * 256 + threadIdx.x;
  if (i >= (long)R * Cpad) return;
  int r = i / Cpad, c = i % Cpad;
  dst[i] = (c < C) ? f2b(src[(long)r * C + c]) : (ushort)0;
}

// Wo [c,c] fp32 -> Wo2 bf16 with column permutation: dst[e, h*d+dd] = src[e, dd*4+h]
__global__ __launch_bounds__(256) void conv_wo(const float* __restrict__ src,
                                               ushort* __restrict__ dst, int c) {
  int d = c >> 2;
  long i = (long)blockIdx.x * 256 + threadIdx.x;
  if (i >= (long)c * c) return;
  int e = i / c, k = i % c;
  dst[i] = f2b(src[(long)e * c + (k % d) * 4 + k / d]);
}

// ---------------------------------------------------------------------------
// MFMA GEMM:  C[m,n] = alpha * sum_k A[m,k]*B[n,k]  (both k-contiguous, bf16)
// 128x128 tile, BK=32, 256 thr = 4 waves (2x2), each wave 64x64 = 4x4 MFMAs
// of 16x16x32 bf16. K must be mult of 32 and all k<K addressable (zero-padded
// where it matters). M/N row indices clamped during staging (garbage rows are
// dropped / zero-padded by the epilogue).
// c_bf16: 1 -> store bf16, cols [Nn,Npad) get 0; 0 -> store fp32, cols < Nn.
// ---------------------------------------------------------------------------
__global__ __launch_bounds__(256) void mfma_abT(
    const ushort* __restrict__ A, long lda, long AsY, long AsZ,
    const ushort* __restrict__ Bm, long ldb, long BsY, long BsZ,
    void* __restrict__ Cv, long ldc, long CsY, long CsZ,
    int M, int Nn, int Npad, int K, float alpha, int c_bf16, int tilesN)
{
  A  += blockIdx.y * AsY + blockIdx.z * AsZ;
  Bm += blockIdx.y * BsY + blockIdx.z * BsZ;

  const int m0 = (blockIdx.x / tilesN) * 128;
  const int n0 = (blockIdx.x % tilesN) * 128;
  const int tid = threadIdx.x;
  const int l = tid & 63, w = tid >> 6;
  const int wy = w >> 1, wx = w & 1;

  __shared__ __align__(16) ushort As[128 * 32];
  __shared__ __align__(16) ushort Bs[128 * 32];

  f32x4 acc[4][4];
  #pragma unroll
  for (int i = 0; i < 4; ++i)
    #pragma unroll
    for (int j = 0; j < 4; ++j) acc[i][j] = (f32x4)0.f;

  // staging: thread t loads 16B (8 bf16) -> LDS flat offset t*16B (+4KB for 2nd)
  const int srow = tid >> 2;
  const int skc  = (tid & 3) * 8;
  int ra0 = m0 + srow;      ra0 = ra0 < M  ? ra0 : M - 1;
  int ra1 = m0 + srow + 64; ra1 = ra1 < M  ? ra1 : M - 1;
  int rb0 = n0 + srow;      rb0 = rb0 < Nn ? rb0 : Nn - 1;
  int rb1 = n0 + srow + 64; rb1 = rb1 < Nn ? rb1 : Nn - 1;
  const ushort* a0 = A  + (long)ra0 * lda + skc;
  const ushort* a1 = A  + (long)ra1 * lda + skc;
  const ushort* b0 = Bm + (long)rb0 * ldb + skc;
  const ushort* b1 = Bm + (long)rb1 * ldb + skc;
  ushort* lA0 = As + srow * 32 + skc;
  ushort* lA1 = As + (srow + 64) * 32 + skc;
  ushort* lB0 = Bs + srow * 32 + skc;
  ushort* lB1 = Bs + (srow + 64) * 32 + skc;

  // fragment read pointers: lane l -> m=l&15 within subtile, k = (l>>4)*8
  const ushort* arp = As + (wy * 64 + (l & 15)) * 32 + (l >> 4) * 8;
  const ushort* brp = Bs + (wx * 64 + (l & 15)) * 32 + (l >> 4) * 8;

  for (int k0 = 0; k0 < K; k0 += 32) {
    __syncthreads();
    gload16(a0 + k0, lA0);
    gload16(a1 + k0, lA1);
    gload16(b0 + k0, lB0);
    gload16(b1 + k0, lB1);
    __syncthreads();
    bf16x8 af[4], bfr[4];
    #pragma unroll
    for (int i = 0; i < 4; ++i) af[i]  = *(const bf16x8*)(arp + i * 512);
    #pragma unroll
    for (int j = 0; j < 4; ++j) bfr[j] = *(const bf16x8*)(brp + j * 512);
    #pragma unroll
    for (int i = 0; i < 4; ++i)
      #pragma unroll
      for (int j = 0; j < 4; ++j)
        acc[i][j] = __builtin_amdgcn_mfma_f32_16x16x32_bf16(af[i], bfr[j], acc[i][j], 0, 0, 0);
  }

  // epilogue: C/D layout col=lane&15, row=(lane>>4)*4+reg  [verified m89/m91]
  const int quad = l >> 4, lc = l & 15;
  if (c_bf16) {
    ushort* C = (ushort*)Cv + blockIdx.y * CsY + blockIdx.z * CsZ;
    #pragma unroll
    for (int i = 0; i < 4; ++i) {
      #pragma unroll
      for (int r = 0; r < 4; ++r) {
        int row = m0 + wy * 64 + i * 16 + quad * 4 + r;
        if (row >= M) continue;
        ushort* Cr = C + (long)row * ldc;
        #pragma unroll
        for (int j = 0; j < 4; ++j) {
          int col = n0 + wx * 64 + j * 16 + lc;
          if (col < Nn) Cr[col] = f2b(acc[i][j][r] * alpha);
          else if (col < Npad) Cr[col] = 0;
        }
      }
    }
  } else {
    float* C = (float*)Cv + blockIdx.y * CsY + blockIdx.z * CsZ;
    #pragma unroll
    for (int i = 0; i < 4; ++i) {
      #pragma unroll
      for (int r = 0; r < 4; ++r) {
        int row = m0 + wy * 64 + i * 16 + quad * 4 + r;
        if (row >= M) continue;
        float* Cr = C + (long)row * ldc;
        #pragma unroll
        for (int j = 0; j < 4; ++j) {
          int col = n0 + wx * 64 + j * 16 + lc;
          if (col < Nn) Cr[col] = acc[i][j][r] * alpha;
        }
      }
    }
  }
}

// ---------------------------------------------------------------------------
// InstanceNorm (per (b,h) over d*240, biased var, eps=1e-5) + row softmax,
// reading fp32 sc [64,240,240] slices, writing bf16 P_b [64,240,256] (pad 0).
// blockIdx.x = b*H+h, blockIdx.y = scale.
// ---------------------------------------------------------------------------
__global__ __launch_bounds__(256) void inorm_softmax_b(const float* __restrict__ sc,
                                                       ushort* __restrict__ P) {
  const int doffs[4] = {0, 16, 48, 112};
  const int dss[4]   = {16, 32, 64, 128};
  const int d = dss[blockIdx.y], off = doffs[blockIdx.y];
  const float* S = sc + (long)blockIdx.x * SC_ + off * D240;
  ushort* Pp = P + ((long)blockIdx.x * D240 + off) * 256;
  const int n = d * D240;

  float s = 0.f, s2 = 0.f;
  for (int i = threadIdx.x; i < n; i += 256) { float v = S[i]; s += v; s2 += v * v; }
  #pragma unroll
  for (int o = 32; o > 0; o >>= 1) { s += __shfl_down(s, o); s2 += __shfl_down(s2, o); }

  __shared__ float wsum[4], wsum2[4];
  __shared__ float stat[2];
  const int wave = threadIdx.x >> 6, lane = threadIdx.x & 63;
  if (lane == 0) { wsum[wave] = s; wsum2[wave] = s2; }
  __syncthreads();
  if (threadIdx.x == 0) {
    float ts = wsum[0] + wsum[1] + wsum[2] + wsum[3];
    float ts2 = wsum2[0] + wsum2[1] + wsum2[2] + wsum2[3];
    float mean = ts / (float)n;
    float var = ts2 / (float)n - mean * mean;
    stat[0] = mean;
    stat[1] = rsqrtf(var + 1e-5f);
  }
  __syncthreads();
  const float mean = stat[0], rstd = stat[1];

  for (int r = wave; r < d; r += 4) {
    const float* row = S + (long)r * D240;
    ushort* prow = Pp + (long)r * 256;
    float v[4];
    float mx = -1e30f;
    #pragma unroll
    for (int j = 0; j < 4; ++j) {
      int c = lane + j * 64;
      v[j] = (c < D240) ? (row[c] - mean) * rstd : -1e30f;
      mx = fmaxf(mx, v[j]);
    }
    #pragma unroll
    for (int o = 32; o > 0; o >>= 1) mx = fmaxf(mx, __shfl_xor(mx, o));
    float sum = 0.f;
    #pragma unroll
    for (int j = 0; j < 4; ++j) {
      int c = lane + j * 64;
      v[j] = (c < D240) ? __expf(v[j] - mx) : 0.f;
      sum += v[j];
    }
    #pragma unroll
    for (int o = 32; o > 0; o >>= 1) sum += __shfl_xor(sum, o);
    float inv = 1.f / sum;
    #pragma unroll
    for (int j = 0; j < 4; ++j) {
      int c = lane + j * 64;
      prow[c] = (c < D240) ? f2b(v[j] * inv) : (ushort)0;
    }
  }
}

// ---------------------------------------------------------------------------
// launch
// ---------------------------------------------------------------------------
extern "C" void kernel_launch(void* const* d_in, const int* in_sizes, int n_in,
                              void* d_out, int out_size, void* d_ws, size_t ws_size,
                              hipStream_t stream) {
  const float* emb[4] = {(const float*)d_in[0], (const float*)d_in[1],
                         (const float*)d_in[2], (const float*)d_in[3]};
  const float* emb_all = (const float*)d_in[4];
  const float* Wq[4] = {(const float*)d_in[5], (const float*)d_in[6],
                        (const float*)d_in[7], (const float*)d_in[8]};
  const float* Wk = (const float*)d_in[9];
  const float* Wv = (const float*)d_in[10];
  const float* Wo[4] = {(const float*)d_in[11], (const float*)d_in[12],
                        (const float*)d_in[13], (const float*)d_in[14]};
  float* out = (float*)d_out;
  float* sc  = (float*)d_out;   // fp32 scores scratch inside out buffer (dead before out-proj)

  // bf16 workspace layout (ushort elems), total 164.7 MB:
  ushort* wsb     = (ushort*)d_ws;
  ushort* heads_b = wsb;               // [B,H,N,256] 32 MB -> dead after K/V proj
  ushort* ctx2    = wsb;               // [B,N,960]   (aliases heads_b)
  ushort* emb_b   = wsb + 16777216;    // [B,N,1024]  33.5 MB -> dead after Q-proj
  ushort* P_b     = wsb + 16777216;    // [64,240,256] (aliases emb_b)
  ushort* Q_T     = wsb + 33554432;    // [B,H,240,1024]
  ushort* Kh_T    = wsb + 49283072;    // [B,H,240,1024]
  ushort* Vh      = wsb + 65011712;    // [B,H,1024,256]
  ushort* wts     = wsb + 81788928;
  ushort* Wk_b = wts;                  // [240,256]
  ushort* Wv_b = wts + 61440;          // [240,256]
  ushort* Wq_b = wts + 122880;         // packed per scale
  ushort* Wo_b = wts + 210944;         // permuted, packed per scale

  const int dss[4]  = {16, 32, 64, 128};
  const int dps[4]  = {32, 32, 64, 128};
  const int soff[4] = {0, 128, 256, 512};
  const int qoff[4] = {0, 16, 48, 112};
  const int coff[4] = {0, 64, 192, 448};
  const int qw[4]   = {0, 2048, 6144, 22528};
  const int wo[4]   = {0, 4096, 20480, 86016};
  const long ooff[4] = {0, 1048576, 3145728, 7340032};
  const float alpha_s = 1.0f / sqrtf(960.0f);

  // conversions
  make_heads_b<<<dim3(B_ * N_), 256, 0, stream>>>(emb_all, heads_b);
  conv_emb<<<dim3(B_ * N_), 256, 0, stream>>>(emb[0], emb[1], emb[2], emb[3], emb_b);
  conv_pad<<<dim3((240 * 256 + 255) / 256), 256, 0, stream>>>(Wk, Wk_b, 240, 240, 256);
  conv_pad<<<dim3((240 * 256 + 255) / 256), 256, 0, stream>>>(Wv, Wv_b, 240, 240, 256);
  for (int i = 0; i < 4; ++i) {
    int d = dss[i], dp = dps[i];
    conv_pad<<<dim3((4 * d * dp + 255) / 256), 256, 0, stream>>>(Wq[i], Wq_b + qw[i], 4 * d, d, dp);
    int c = 4 * d;
    conv_wo<<<dim3((c * c + 255) / 256), 256, 0, stream>>>(Wo[i], Wo_b + wo[i], c);
  }

  // K-proj (transposed output): Kh_T[bh][e][n] = sum_d Wk[e,d]*heads[bh,n,d]
  mfma_abT<<<dim3(16, 64, 1), 256, 0, stream>>>(
      Wk_b, 256, 0, 0,
      heads_b, 256, 1024L * 256, 0,
      Kh_T, 1024, 240L * 1024, 0,
      240, 1024, 1024, 256, 1.f, 1, 8);

  // V-proj (normal): Vh[bh][n][e], e-pad 256 zeroed
  mfma_abT<<<dim3(16, 64, 1), 256, 0, stream>>>(
      heads_b, 256, 1024L * 256, 0,
      Wv_b, 256, 0, 0,
      Vh, 256, 1024L * 256, 0,
      1024, 240, 256, 256, 1.f, 1, 2);

  // Q-proj per scale (transposed output into Q_T row slice)
  for (int i = 0; i < 4; ++i) {
    int d = dss[i], dp = dps[i];
    mfma_abT<<<dim3(8, H_, B_), 256, 0, stream>>>(
        Wq_b + qw[i], dp, (long)d * dp, 0,
        emb_b + soff[i], 1024, (long)dp, 1024L * 1024,
        Q_T + (long)qoff[i] * 1024, 1024, 240L * 1024, 4L * 240 * 1024,
        d, 1024, 1024, dp, 1.f, 1, 8);
  }

  // fused scores: sc[bh][r][k] = alpha * sum_n Q_T[bh,r,n]*Kh_T[bh,k,n]  (fp32)
  mfma_abT<<<dim3(4, 64, 1), 256, 0, stream>>>(
      Q_T, 1024, 240L * 1024, 0,
      Kh_T, 1024, 240L * 1024, 0,
      sc, 240, (long)SC_, 0,
      240, 240, 240, 1024, alpha_s, 0, 2);

  // InstanceNorm + softmax -> bf16 probs (k-pad 256 zeroed)
  inorm_softmax_b<<<dim3(64, 4), 256, 0, stream>>>(sc, P_b);

  // ctx per scale: ctx2[b,n, coff + h*d + dd] = sum_k Vh[b,h,n,k]*P[b,h,qoff+dd,k]
  for (int i = 0; i < 4; ++i) {
    int d = dss[i];
    mfma_abT<<<dim3(8, H_, B_), 256, 0, stream>>>(
        Vh, 256, 1024L * 256, 4L * 1024 * 256,
        P_b + (long)qoff[i] * 256, 256, 240L * 256, 4L * 240 * 256,
        ctx2 + coff[i], 960, (long)d, 960L * 1024,
        1024, d, d, 256, 1.f, 1, 1);
  }

  // out-proj per scale: out[bn,e] = sum_k ctx2[bn, coff+k]*Wo2[e,k]  (fp32 final)
  for (int i = 0; i < 4; ++i) {
    int c = 4 * dss[i];
    int tn = (c + 127) / 128;
    mfma_abT<<<dim3(128 * tn, 1, 1), 256, 0, stream>>>(
        ctx2 + coff[i], 960, 0, 0,
        Wo_b + wo[i], c, 0, 0,
        out + ooff[i], c, 0, 0,
        B_ * N_, c, c, c, 1.f, 0, tn);
  }
}

// Round 4
// 418.452 us; speedup vs baseline: 4.5513x; 1.2101x over previous
//
#include <hip/hip_runtime.h>
#include <hip/hip_bf16.h>
#include <math.h>

#define B_   16
#define N_   1024
#define H_   4
#define D240 240
#define SC_  57600   // 240*240

typedef unsigned short ushort;
typedef __attribute__((ext_vector_type(8))) short bf16x8;
typedef __attribute__((ext_vector_type(4))) float f32x4;

__device__ __forceinline__ ushort f2b(float v) {
  __hip_bfloat16 h = __float2bfloat16(v);
  return *reinterpret_cast<ushort*>(&h);
}

__device__ __forceinline__ void gload16(const void* g, void* s) {
  __builtin_amdgcn_global_load_lds((const __attribute__((address_space(1))) void*)g,
                                   (__attribute__((address_space(3))) void*)s, 16, 0, 0);
}

// ---------------------------------------------------------------------------
// conv_inputs: emb_all -> heads_b [B,H,N,256]; emb1..4 -> emb_h [B,H,N,256]
// per-h channel k: [0,16)=s0, [16,48)=s1, [48,112)=s2, [112,240)=s3, pad 0.
// heads source: emb_all segments at 0/64/192/448; emb_h source: emb_i directly.
// ushort2 stores (segment boundaries are even; pairs never straddle).
// ---------------------------------------------------------------------------
__global__ __launch_bounds__(256) void conv_inputs(const float* __restrict__ emb_all,
                                                   const float* __restrict__ e1,
                                                   const float* __restrict__ e2,
                                                   const float* __restrict__ e3,
                                                   const float* __restrict__ e4,
                                                   ushort* __restrict__ heads,
                                                   ushort* __restrict__ embh) {
  const int bn = blockIdx.x;
  const int b = bn >> 10, n = bn & 1023;
  const float* ha = emb_all + (long)bn * 960;

  for (int u = threadIdx.x; u < 512; u += 256) {
    const int slot = u * 2;
    const int h = slot >> 8, k = slot & 255;
    long dsti = (((long)b * H_ + h) * N_ + n) * 256 + k;
    // heads from emb_all
    float hv0 = 0.f, hv1 = 0.f;
    if (k < 16)       { const float* p = ha + h * 16 + k;              hv0 = p[0]; hv1 = p[1]; }
    else if (k < 48)  { const float* p = ha + 64 + h * 32 + (k - 16);  hv0 = p[0]; hv1 = p[1]; }
    else if (k < 112) { const float* p = ha + 192 + h * 64 + (k - 48); hv0 = p[0]; hv1 = p[1]; }
    else if (k < 240) { const float* p = ha + 448 + h * 128 + (k - 112); hv0 = p[0]; hv1 = p[1]; }
    ushort2 hw; hw.x = f2b(hv0); hw.y = f2b(hv1);
    *(ushort2*)(heads + dsti) = hw;
    // emb_h from emb1..4
    float ev0 = 0.f, ev1 = 0.f;
    if (k < 16)       { const float* p = e1 + (long)bn * 64  + h * 16  + k;         ev0 = p[0]; ev1 = p[1]; }
    else if (k < 48)  { const float* p = e2 + (long)bn * 128 + h * 32  + (k - 16);  ev0 = p[0]; ev1 = p[1]; }
    else if (k < 112) { const float* p = e3 + (long)bn * 256 + h * 64  + (k - 48);  ev0 = p[0]; ev1 = p[1]; }
    else if (k < 240) { const float* p = e4 + (long)bn * 512 + h * 128 + (k - 112); ev0 = p[0]; ev1 = p[1]; }
    ushort2 ew; ew.x = f2b(ev0); ew.y = f2b(ev1);
    *(ushort2*)(embh + dsti) = ew;
  }
}

// ---------------------------------------------------------------------------
// conv_weights: one kernel for Wk_b, Wv_b, Wq_bd (block-diag per head), Wo_b
// (permuted). Layout in wts (ushort):
//   [0,61440)        Wk_b  [240,256] pad
//   [61440,122880)   Wv_b  [240,256] pad
//   [122880,368640)  Wq_bd [4][240][256] block-diag
//   [368640,716800)  Wo_b  packed {64^2,128^2,256^2,512^2} col-permuted
// ---------------------------------------------------------------------------
__global__ __launch_bounds__(256) void conv_weights(
    const float* __restrict__ Wk, const float* __restrict__ Wv,
    const float* __restrict__ q1, const float* __restrict__ q2,
    const float* __restrict__ q3, const float* __restrict__ q4,
    const float* __restrict__ o1, const float* __restrict__ o2,
    const float* __restrict__ o3, const float* __restrict__ o4,
    ushort* __restrict__ wts) {
  long i = (long)blockIdx.x * 256 + threadIdx.x;
  if (i >= 716800) return;
  float v = 0.f;
  if (i < 122880) {
    const float* src = (i < 61440) ? Wk : Wv;
    long j = (i < 61440) ? i : i - 61440;
    int r = j / 256, k = j % 256;
    if (k < 240) v = src[(long)r * 240 + k];
  } else if (i < 368640) {
    long j = i - 122880;
    int h = j / 61440; int rem = j % 61440;
    int r = rem / 256, k = rem % 256;
    int s = r < 16 ? 0 : r < 48 ? 1 : r < 112 ? 2 : 3;
    const int dss[4] = {16, 32, 64, 128};
    const int qf[4]  = {0, 16, 48, 112};
    const float* qs[4] = {q1, q2, q3, q4};
    int d = dss[s], off = qf[s];
    if (k >= off && k < off + d)
      v = qs[s][((long)(h * d + (r - off))) * d + (k - off)];
  } else {
    long j = i - 368640;
    int s = j < 4096 ? 0 : j < 20480 ? 1 : j < 86016 ? 2 : 3;
    const long base[4] = {0, 4096, 20480, 86016};
    const int cs[4] = {64, 128, 256, 512};
    const float* os[4] = {o1, o2, o3, o4};
    long rem = j - base[s];
    int c = cs[s], d = c >> 2;
    int e = rem / c, kk = rem % c;
    v = os[s][(long)e * c + (kk % d) * 4 + kk / d];
  }
  wts[i] = f2b(v);
}

// ---------------------------------------------------------------------------
// MFMA GEMM:  C[m,n] = alpha * sum_k A[m,k]*B[n,k]  (both k-contiguous, bf16)
// 128x128 tile, BK=32, 4 waves 2x2, 16x16x32 MFMA. (verified round 3)
// ---------------------------------------------------------------------------
__global__ __launch_bounds__(256) void mfma_abT(
    const ushort* __restrict__ A, long lda, long AsY, long AsZ,
    const ushort* __restrict__ Bm, long ldb, long BsY, long BsZ,
    void* __restrict__ Cv, long ldc, long CsY, long CsZ,
    int M, int Nn, int Npad, int K, float alpha, int c_bf16, int tilesN)
{
  A  += blockIdx.y * AsY + blockIdx.z * AsZ;
  Bm += blockIdx.y * BsY + blockIdx.z * BsZ;

  const int m0 = (blockIdx.x / tilesN) * 128;
  const int n0 = (blockIdx.x % tilesN) * 128;
  const int tid = threadIdx.x;
  const int l = tid & 63, w = tid >> 6;
  const int wy = w >> 1, wx = w & 1;

  __shared__ __align__(16) ushort As[128 * 32];
  __shared__ __align__(16) ushort Bs[128 * 32];

  f32x4 acc[4][4];
  #pragma unroll
  for (int i = 0; i < 4; ++i)
    #pragma unroll
    for (int j = 0; j < 4; ++j) acc[i][j] = (f32x4)0.f;

  const int srow = tid >> 2;
  const int skc  = (tid & 3) * 8;
  int ra0 = m0 + srow;      ra0 = ra0 < M  ? ra0 : M - 1;
  int ra1 = m0 + srow + 64; ra1 = ra1 < M  ? ra1 : M - 1;
  int rb0 = n0 + srow;      rb0 = rb0 < Nn ? rb0 : Nn - 1;
  int rb1 = n0 + srow + 64; rb1 = rb1 < Nn ? rb1 : Nn - 1;
  const ushort* a0 = A  + (long)ra0 * lda + skc;
  const ushort* a1 = A  + (long)ra1 * lda + skc;
  const ushort* b0 = Bm + (long)rb0 * ldb + skc;
  const ushort* b1 = Bm + (long)rb1 * ldb + skc;
  ushort* lA0 = As + srow * 32 + skc;
  ushort* lA1 = As + (srow + 64) * 32 + skc;
  ushort* lB0 = Bs + srow * 32 + skc;
  ushort* lB1 = Bs + (srow + 64) * 32 + skc;

  const ushort* arp = As + (wy * 64 + (l & 15)) * 32 + (l >> 4) * 8;
  const ushort* brp = Bs + (wx * 64 + (l & 15)) * 32 + (l >> 4) * 8;

  for (int k0 = 0; k0 < K; k0 += 32) {
    __syncthreads();
    gload16(a0 + k0, lA0);
    gload16(a1 + k0, lA1);
    gload16(b0 + k0, lB0);
    gload16(b1 + k0, lB1);
    __syncthreads();
    bf16x8 af[4], bfr[4];
    #pragma unroll
    for (int i = 0; i < 4; ++i) af[i]  = *(const bf16x8*)(arp + i * 512);
    #pragma unroll
    for (int j = 0; j < 4; ++j) bfr[j] = *(const bf16x8*)(brp + j * 512);
    #pragma unroll
    for (int i = 0; i < 4; ++i)
      #pragma unroll
      for (int j = 0; j < 4; ++j)
        acc[i][j] = __builtin_amdgcn_mfma_f32_16x16x32_bf16(af[i], bfr[j], acc[i][j], 0, 0, 0);
  }

  const int quad = l >> 4, lc = l & 15;
  if (c_bf16) {
    ushort* C = (ushort*)Cv + blockIdx.y * CsY + blockIdx.z * CsZ;
    #pragma unroll
    for (int i = 0; i < 4; ++i) {
      #pragma unroll
      for (int r = 0; r < 4; ++r) {
        int row = m0 + wy * 64 + i * 16 + quad * 4 + r;
        if (row >= M) continue;
        ushort* Cr = C + (long)row * ldc;
        #pragma unroll
        for (int j = 0; j < 4; ++j) {
          int col = n0 + wx * 64 + j * 16 + lc;
          if (col < Nn) Cr[col] = f2b(acc[i][j][r] * alpha);
          else if (col < Npad) Cr[col] = 0;
        }
      }
    }
  } else {
    float* C = (float*)Cv + blockIdx.y * CsY + blockIdx.z * CsZ;
    #pragma unroll
    for (int i = 0; i < 4; ++i) {
      #pragma unroll
      for (int r = 0; r < 4; ++r) {
        int row = m0 + wy * 64 + i * 16 + quad * 4 + r;
        if (row >= M) continue;
        float* Cr = C + (long)row * ldc;
        #pragma unroll
        for (int j = 0; j < 4; ++j) {
          int col = n0 + wx * 64 + j * 16 + lc;
          if (col < Nn) Cr[col] = acc[i][j][r] * alpha;
        }
      }
    }
  }
}

// ---------------------------------------------------------------------------
// mfma_ctx: fused ctx GEMM. A=Vh[bh] [1024,256], B=P_b[bh] [240,256], K=256.
// Epilogue maps col (0..239) -> output channel coff[s] + h*d_s + (col-qoff[s])
// writing bf16 into ctx2 [B,N,960].
// ---------------------------------------------------------------------------
__global__ __launch_bounds__(256) void mfma_ctx(const ushort* __restrict__ V,
                                                const ushort* __restrict__ P,
                                                ushort* __restrict__ ctx2) {
  const int h = blockIdx.y, b = blockIdx.z;
  const ushort* A  = V + (((long)b * H_ + h) * 1024) * 256;
  const ushort* Bm = P + (((long)b * H_ + h) * 240) * 256;

  const int m0 = (blockIdx.x >> 1) * 128;
  const int n0 = (blockIdx.x & 1) * 128;
  const int tid = threadIdx.x;
  const int l = tid & 63, w = tid >> 6;
  const int wy = w >> 1, wx = w & 1;

  __shared__ __align__(16) ushort As[128 * 32];
  __shared__ __align__(16) ushort Bs[128 * 32];

  f32x4 acc[4][4];
  #pragma unroll
  for (int i = 0; i < 4; ++i)
    #pragma unroll
    for (int j = 0; j < 4; ++j) acc[i][j] = (f32x4)0.f;

  const int srow = tid >> 2;
  const int skc  = (tid & 3) * 8;
  int rb0 = n0 + srow;      rb0 = rb0 < 240 ? rb0 : 239;
  int rb1 = n0 + srow + 64; rb1 = rb1 < 240 ? rb1 : 239;
  const ushort* a0 = A  + (long)(m0 + srow) * 256 + skc;
  const ushort* a1 = A  + (long)(m0 + srow + 64) * 256 + skc;
  const ushort* b0 = Bm + (long)rb0 * 256 + skc;
  const ushort* b1 = Bm + (long)rb1 * 256 + skc;
  ushort* lA0 = As + srow * 32 + skc;
  ushort* lA1 = As + (srow + 64) * 32 + skc;
  ushort* lB0 = Bs + srow * 32 + skc;
  ushort* lB1 = Bs + (srow + 64) * 32 + skc;

  const ushort* arp = As + (wy * 64 + (l & 15)) * 32 + (l >> 4) * 8;
  const ushort* brp = Bs + (wx * 64 + (l & 15)) * 32 + (l >> 4) * 8;

  for (int k0 = 0; k0 < 256; k0 += 32) {
    __syncthreads();
    gload16(a0 + k0, lA0);
    gload16(a1 + k0, lA1);
    gload16(b0 + k0, lB0);
    gload16(b1 + k0, lB1);
    __syncthreads();
    bf16x8 af[4], bfr[4];
    #pragma unroll
    for (int i = 0; i < 4; ++i) af[i]  = *(const bf16x8*)(arp + i * 512);
    #pragma unroll
    for (int j = 0; j < 4; ++j) bfr[j] = *(const bf16x8*)(brp + j * 512);
    #pragma unroll
    for (int i = 0; i < 4; ++i)
      #pragma unroll
      for (int j = 0; j < 4; ++j)
        acc[i][j] = __builtin_amdgcn_mfma_f32_16x16x32_bf16(af[i], bfr[j], acc[i][j], 0, 0, 0);
  }

  const int quad = l >> 4, lc = l & 15;
  const int dss[4] = {16, 32, 64, 128};
  const int qf[4]  = {0, 16, 48, 112};
  const int cf[4]  = {0, 64, 192, 448};
  #pragma unroll
  for (int i = 0; i < 4; ++i) {
    #pragma unroll
    for (int r = 0; r < 4; ++r) {
      int row = m0 + wy * 64 + i * 16 + quad * 4 + r;   // < 1024 always
      ushort* Cr = ctx2 + ((long)b * N_ + row) * 960;
      #pragma unroll
      for (int j = 0; j < 4; ++j) {
        int col = n0 + wx * 64 + j * 16 + lc;
        if (col < 240) {
          int s = col < 16 ? 0 : col < 48 ? 1 : col < 112 ? 2 : 3;
          int chan = cf[s] + h * dss[s] + (col - qf[s]);
          Cr[chan] = f2b(acc[i][j][r]);
        }
      }
    }
  }
}

// ---------------------------------------------------------------------------
// in_stats: per (bh, scale) mean/rstd over the d*240 slice (float4 reads).
// ---------------------------------------------------------------------------
__global__ __launch_bounds__(256) void in_stats(const float* __restrict__ sc,
                                                float* __restrict__ stats) {
  const int doffs[4] = {0, 16, 48, 112};
  const int dss[4]   = {16, 32, 64, 128};
  const int bh = blockIdx.x, sidx = blockIdx.y;
  const float4* S4 = (const float4*)(sc + (long)bh * SC_ + doffs[sidx] * D240);
  const int n4 = dss[sidx] * 60;   // d*240/4

  float s = 0.f, s2 = 0.f;
  for (int i = threadIdx.x; i < n4; i += 256) {
    float4 v = S4[i];
    s  += v.x + v.y + v.z + v.w;
    s2 += v.x * v.x + v.y * v.y + v.z * v.z + v.w * v.w;
  }
  #pragma unroll
  for (int o = 32; o > 0; o >>= 1) { s += __shfl_down(s, o); s2 += __shfl_down(s2, o); }

  __shared__ float wsum[4], wsum2[4];
  const int wave = threadIdx.x >> 6, lane = threadIdx.x & 63;
  if (lane == 0) { wsum[wave] = s; wsum2[wave] = s2; }
  __syncthreads();
  if (threadIdx.x == 0) {
    float n = (float)(n4 * 4);
    float ts = wsum[0] + wsum[1] + wsum[2] + wsum[3];
    float ts2 = wsum2[0] + wsum2[1] + wsum2[2] + wsum2[3];
    float mean = ts / n;
    float var = ts2 / n - mean * mean;
    stats[(bh * 4 + sidx) * 2]     = mean;
    stats[(bh * 4 + sidx) * 2 + 1] = rsqrtf(var + 1e-5f);
  }
}

// ---------------------------------------------------------------------------
// sm_apply: one wave per row (240 rows per bh). Normalize + softmax -> bf16 P.
// grid (60, 64).
// ---------------------------------------------------------------------------
__global__ __launch_bounds__(256) void sm_apply(const float* __restrict__ sc,
                                                const float* __restrict__ stats,
                                                ushort* __restrict__ P) {
  const int bh = blockIdx.y;
  const int row = blockIdx.x * 4 + (threadIdx.x >> 6);
  const int lane = threadIdx.x & 63;
  const int s = row < 16 ? 0 : row < 48 ? 1 : row < 112 ? 2 : 3;
  const float mean = stats[(bh * 4 + s) * 2];
  const float rstd = stats[(bh * 4 + s) * 2 + 1];
  const float* r = sc + (long)bh * SC_ + (long)row * D240;
  ushort* p = P + ((long)bh * D240 + row) * 256;

  float v[4];
  float mx = -1e30f;
  #pragma unroll
  for (int j = 0; j < 4; ++j) {
    int c = lane + j * 64;
    v[j] = (c < D240) ? (r[c] - mean) * rstd : -1e30f;
    mx = fmaxf(mx, v[j]);
  }
  #pragma unroll
  for (int o = 32; o > 0; o >>= 1) mx = fmaxf(mx, __shfl_xor(mx, o));
  float sum = 0.f;
  #pragma unroll
  for (int j = 0; j < 4; ++j) {
    int c = lane + j * 64;
    v[j] = (c < D240) ? __expf(v[j] - mx) : 0.f;
    sum += v[j];
  }
  #pragma unroll
  for (int o = 32; o > 0; o >>= 1) sum += __shfl_xor(sum, o);
  float inv = 1.f / sum;
  #pragma unroll
  for (int j = 0; j < 4; ++j) {
    int c = lane + j * 64;
    p[c] = (c < D240) ? f2b(v[j] * inv) : (ushort)0;
  }
}

// ---------------------------------------------------------------------------
// launch
// ---------------------------------------------------------------------------
extern "C" void kernel_launch(void* const* d_in, const int* in_sizes, int n_in,
                              void* d_out, int out_size, void* d_ws, size_t ws_size,
                              hipStream_t stream) {
  const float* emb[4] = {(const float*)d_in[0], (const float*)d_in[1],
                         (const float*)d_in[2], (const float*)d_in[3]};
  const float* emb_all = (const float*)d_in[4];
  const float* Wq[4] = {(const float*)d_in[5], (const float*)d_in[6],
                        (const float*)d_in[7], (const float*)d_in[8]};
  const float* Wk = (const float*)d_in[9];
  const float* Wv = (const float*)d_in[10];
  const float* Wo[4] = {(const float*)d_in[11], (const float*)d_in[12],
                        (const float*)d_in[13], (const float*)d_in[14]};
  float* out = (float*)d_out;
  float* sc  = (float*)d_out;   // fp32 scores scratch in out buffer (dead before out-proj)

  // ws layout (ushort offsets), ~165 MB total:
  ushort* wsb     = (ushort*)d_ws;
  ushort* heads_b = wsb;               // [B,H,N,256] -> dead after K/V proj
  ushort* ctx2    = wsb;               // [B,N,960]   (aliases heads_b)
  ushort* emb_h   = wsb + 16777216;    // [B,H,N,256] -> dead after Q-proj
  ushort* P_b     = wsb + 16777216;    // [64,240,256] (aliases emb_h)
  ushort* Q_T     = wsb + 33554432;    // [B,H,240,1024]
  ushort* Kh_T    = wsb + 49283072;    // [B,H,240,1024]
  ushort* Vh      = wsb + 65011712;    // [B,H,1024,256]
  ushort* wts     = wsb + 81788928;    // 716800: Wk_b|Wv_b|Wq_bd|Wo_b
  ushort* Wk_b  = wts;
  ushort* Wv_b  = wts + 61440;
  ushort* Wq_bd = wts + 122880;
  ushort* Wo_b  = wts + 368640;
  float*  stats = (float*)(wsb + 82505728);   // [64][4][2] fp32

  const long sbh256 = 1024L * 256;             // bh stride of [.,.,N,256]
  const int  wo[4]   = {0, 4096, 20480, 86016};
  const long ooff[4] = {0, 1048576, 3145728, 7340032};
  const int  cs[4]   = {64, 128, 256, 512};
  const float alpha_s = 1.0f / sqrtf(960.0f);

  conv_inputs<<<dim3(B_ * N_), 256, 0, stream>>>(emb_all, emb[0], emb[1], emb[2], emb[3],
                                                 heads_b, emb_h);
  conv_weights<<<dim3(2800), 256, 0, stream>>>(Wk, Wv, Wq[0], Wq[1], Wq[2], Wq[3],
                                               Wo[0], Wo[1], Wo[2], Wo[3], wts);

  // K-proj (transposed): Kh_T[bh][e][n] = sum_d Wk[e,d]*heads[bh,n,d]
  mfma_abT<<<dim3(16, 64, 1), 256, 0, stream>>>(
      Wk_b, 256, 0, 0,
      heads_b, 256, sbh256, 0,
      Kh_T, 1024, 240L * 1024, 0,
      240, 1024, 1024, 256, 1.f, 1, 8);

  // V-proj: Vh[bh][n][e], e-pad to 256 zeroed
  mfma_abT<<<dim3(16, 64, 1), 256, 0, stream>>>(
      heads_b, 256, sbh256, 0,
      Wv_b, 256, 0, 0,
      Vh, 256, sbh256, 0,
      1024, 240, 256, 256, 1.f, 1, 2);

  // Q-proj fused across scales (block-diag weights): Q_T[b,h,r,n]
  mfma_abT<<<dim3(16, H_, B_), 256, 0, stream>>>(
      Wq_bd, 256, 240L * 256, 0,
      emb_h, 256, sbh256, (long)H_ * sbh256,
      Q_T, 1024, 240L * 1024, 4L * 240 * 1024,
      240, 1024, 1024, 256, 1.f, 1, 8);

  // fused scores: sc[bh][r][k] = alpha * sum_n Q_T[bh,r,n]*Kh_T[bh,k,n]  (fp32)
  mfma_abT<<<dim3(4, 64, 1), 256, 0, stream>>>(
      Q_T, 1024, 240L * 1024, 0,
      Kh_T, 1024, 240L * 1024, 0,
      sc, 240, (long)SC_, 0,
      240, 240, 240, 1024, alpha_s, 0, 2);

  // InstanceNorm stats + softmax apply -> bf16 probs
  in_stats<<<dim3(64, 4), 256, 0, stream>>>(sc, stats);
  sm_apply<<<dim3(60, 64), 256, 0, stream>>>(sc, stats, P_b);

  // fused ctx: ctx2[b,n,chan(col,h)] = sum_k Vh[bh,n,k]*P[bh,col,k]
  mfma_ctx<<<dim3(16, H_, B_), 256, 0, stream>>>(Vh, P_b, ctx2);

  // out-proj per scale: out[bn,e] = sum_k ctx2[bn, coff+k]*Wo_b[e,k]  (fp32)
  const int coff[4] = {0, 64, 192, 448};
  for (int i = 0; i < 4; ++i) {
    int c = cs[i];
    int tn = (c + 127) / 128;
    mfma_abT<<<dim3(128 * tn, 1, 1), 256, 0, stream>>>(
        ctx2 + coff[i], 960, 0, 0,
        Wo_b + wo[i], c, 0, 0,
        out + ooff[i], c, 0, 0,
        B_ * N_, c, c, c, 1.f, 0, tn);
  }
}

// Round 5
// 367.119 us; speedup vs baseline: 5.1876x; 1.1398x over previous
//
#include <hip/hip_runtime.h>
#include <hip/hip_bf16.h>
#include <math.h>

#define B_   16
#define N_   1024
#define H_   4
#define D240 240
#define SC_  57600   // 240*240

typedef unsigned short ushort;
typedef __attribute__((ext_vector_type(8))) short bf16x8;
typedef __attribute__((ext_vector_type(8))) unsigned short u16x8;
typedef __attribute__((ext_vector_type(4))) float f32x4;

__device__ __forceinline__ ushort f2b(float v) {
  __hip_bfloat16 h = __float2bfloat16(v);
  return *reinterpret_cast<ushort*>(&h);
}

__device__ __forceinline__ void gload16(const void* g, void* s) {
  __builtin_amdgcn_global_load_lds((const __attribute__((address_space(1))) void*)g,
                                   (__attribute__((address_space(3))) void*)s, 16, 0, 0);
}

// ---------------------------------------------------------------------------
// conv_inputs (vectorized): emb_all -> heads_b [B,H,N,256]; emb1..4 -> emb_h.
// One thread per 8-channel group: 2x float4 loads, 1x 16B store.
// Segment boundaries (16/48/112/240) are multiples of 8 -> no straddle.
// thread t: which = t>>7 (0 heads, 1 embh), gg = t&127, h = gg>>5, k0 = (gg&31)*8.
// ---------------------------------------------------------------------------
__global__ __launch_bounds__(256) void conv_inputs(const float* __restrict__ emb_all,
                                                   const float* __restrict__ e1,
                                                   const float* __restrict__ e2,
                                                   const float* __restrict__ e3,
                                                   const float* __restrict__ e4,
                                                   ushort* __restrict__ heads,
                                                   ushort* __restrict__ embh) {
  const int bn = blockIdx.x;
  const int b = bn >> 10, n = bn & 1023;
  const int t = threadIdx.x;
  const int which = t >> 7;
  const int gg = t & 127;
  const int h = gg >> 5;
  const int k0 = (gg & 31) * 8;

  ushort* dst = (which ? embh : heads) + (((long)b * H_ + h) * N_ + n) * 256 + k0;

  float4 p0 = {0.f, 0.f, 0.f, 0.f}, p1 = {0.f, 0.f, 0.f, 0.f};
  if (k0 < 240) {
    const float* src;
    if (which == 0) {
      const float* ha = emb_all + (long)bn * 960;
      if (k0 < 16)       src = ha + h * 16 + k0;
      else if (k0 < 48)  src = ha + 64  + h * 32  + (k0 - 16);
      else if (k0 < 112) src = ha + 192 + h * 64  + (k0 - 48);
      else               src = ha + 448 + h * 128 + (k0 - 112);
    } else {
      if (k0 < 16)       src = e1 + (long)bn * 64  + h * 16  + k0;
      else if (k0 < 48)  src = e2 + (long)bn * 128 + h * 32  + (k0 - 16);
      else if (k0 < 112) src = e3 + (long)bn * 256 + h * 64  + (k0 - 48);
      else               src = e4 + (long)bn * 512 + h * 128 + (k0 - 112);
    }
    p0 = *(const float4*)src;
    p1 = *(const float4*)(src + 4);
  }
  u16x8 w;
  w[0] = f2b(p0.x); w[1] = f2b(p0.y); w[2] = f2b(p0.z); w[3] = f2b(p0.w);
  w[4] = f2b(p1.x); w[5] = f2b(p1.y); w[6] = f2b(p1.z); w[7] = f2b(p1.w);
  *(u16x8*)dst = w;
}

// ---------------------------------------------------------------------------
// conv_weights: Wk_b | Wv_b | Wq_bd (block-diag per head) | Wo_b (col-permuted)
// ---------------------------------------------------------------------------
__global__ __launch_bounds__(256) void conv_weights(
    const float* __restrict__ Wk, const float* __restrict__ Wv,
    const float* __restrict__ q1, const float* __restrict__ q2,
    const float* __restrict__ q3, const float* __restrict__ q4,
    const float* __restrict__ o1, const float* __restrict__ o2,
    const float* __restrict__ o3, const float* __restrict__ o4,
    ushort* __restrict__ wts) {
  long i = (long)blockIdx.x * 256 + threadIdx.x;
  if (i >= 716800) return;
  float v = 0.f;
  if (i < 122880) {
    const float* src = (i < 61440) ? Wk : Wv;
    long j = (i < 61440) ? i : i - 61440;
    int r = j / 256, k = j % 256;
    if (k < 240) v = src[(long)r * 240 + k];
  } else if (i < 368640) {
    long j = i - 122880;
    int h = j / 61440; int rem = j % 61440;
    int r = rem / 256, k = rem % 256;
    int s = r < 16 ? 0 : r < 48 ? 1 : r < 112 ? 2 : 3;
    const int dss[4] = {16, 32, 64, 128};
    const int qf[4]  = {0, 16, 48, 112};
    const float* qs[4] = {q1, q2, q3, q4};
    int d = dss[s], off = qf[s];
    if (k >= off && k < off + d)
      v = qs[s][((long)(h * d + (r - off))) * d + (k - off)];
  } else {
    long j = i - 368640;
    int s = j < 4096 ? 0 : j < 20480 ? 1 : j < 86016 ? 2 : 3;
    const long base[4] = {0, 4096, 20480, 86016};
    const int cs[4] = {64, 128, 256, 512};
    const float* os[4] = {o1, o2, o3, o4};
    long rem = j - base[s];
    int c = cs[s], d = c >> 2;
    int e = rem / c, kk = rem % c;
    v = os[s][(long)e * c + (kk % d) * 4 + kk / d];
  }
  wts[i] = f2b(v);
}

// ---------------------------------------------------------------------------
// MFMA GEMM:  C[m,n] = alpha * sum_k A[m,k]*B[n,k]  (k-contiguous bf16)
// 128x128 tile, BK=32, 4 waves 2x2, 16x16x32 MFMA. (verified round 3)
// ---------------------------------------------------------------------------
__global__ __launch_bounds__(256) void mfma_abT(
    const ushort* __restrict__ A, long lda, long AsY, long AsZ,
    const ushort* __restrict__ Bm, long ldb, long BsY, long BsZ,
    void* __restrict__ Cv, long ldc, long CsY, long CsZ,
    int M, int Nn, int Npad, int K, float alpha, int c_bf16, int tilesN)
{
  A  += blockIdx.y * AsY + blockIdx.z * AsZ;
  Bm += blockIdx.y * BsY + blockIdx.z * BsZ;

  const int m0 = (blockIdx.x / tilesN) * 128;
  const int n0 = (blockIdx.x % tilesN) * 128;
  const int tid = threadIdx.x;
  const int l = tid & 63, w = tid >> 6;
  const int wy = w >> 1, wx = w & 1;

  __shared__ __align__(16) ushort As[128 * 32];
  __shared__ __align__(16) ushort Bs[128 * 32];

  f32x4 acc[4][4];
  #pragma unroll
  for (int i = 0; i < 4; ++i)
    #pragma unroll
    for (int j = 0; j < 4; ++j) acc[i][j] = (f32x4)0.f;

  const int srow = tid >> 2;
  const int skc  = (tid & 3) * 8;
  int ra0 = m0 + srow;      ra0 = ra0 < M  ? ra0 : M - 1;
  int ra1 = m0 + srow + 64; ra1 = ra1 < M  ? ra1 : M - 1;
  int rb0 = n0 + srow;      rb0 = rb0 < Nn ? rb0 : Nn - 1;
  int rb1 = n0 + srow + 64; rb1 = rb1 < Nn ? rb1 : Nn - 1;
  const ushort* a0 = A  + (long)ra0 * lda + skc;
  const ushort* a1 = A  + (long)ra1 * lda + skc;
  const ushort* b0 = Bm + (long)rb0 * ldb + skc;
  const ushort* b1 = Bm + (long)rb1 * ldb + skc;
  ushort* lA0 = As + srow * 32 + skc;
  ushort* lA1 = As + (srow + 64) * 32 + skc;
  ushort* lB0 = Bs + srow * 32 + skc;
  ushort* lB1 = Bs + (srow + 64) * 32 + skc;

  const ushort* arp = As + (wy * 64 + (l & 15)) * 32 + (l >> 4) * 8;
  const ushort* brp = Bs + (wx * 64 + (l & 15)) * 32 + (l >> 4) * 8;

  for (int k0 = 0; k0 < K; k0 += 32) {
    __syncthreads();
    gload16(a0 + k0, lA0);
    gload16(a1 + k0, lA1);
    gload16(b0 + k0, lB0);
    gload16(b1 + k0, lB1);
    __syncthreads();
    bf16x8 af[4], bfr[4];
    #pragma unroll
    for (int i = 0; i < 4; ++i) af[i]  = *(const bf16x8*)(arp + i * 512);
    #pragma unroll
    for (int j = 0; j < 4; ++j) bfr[j] = *(const bf16x8*)(brp + j * 512);
    #pragma unroll
    for (int i = 0; i < 4; ++i)
      #pragma unroll
      for (int j = 0; j < 4; ++j)
        acc[i][j] = __builtin_amdgcn_mfma_f32_16x16x32_bf16(af[i], bfr[j], acc[i][j], 0, 0, 0);
  }

  const int quad = l >> 4, lc = l & 15;
  if (c_bf16) {
    ushort* C = (ushort*)Cv + blockIdx.y * CsY + blockIdx.z * CsZ;
    #pragma unroll
    for (int i = 0; i < 4; ++i) {
      #pragma unroll
      for (int r = 0; r < 4; ++r) {
        int row = m0 + wy * 64 + i * 16 + quad * 4 + r;
        if (row >= M) continue;
        ushort* Cr = C + (long)row * ldc;
        #pragma unroll
        for (int j = 0; j < 4; ++j) {
          int col = n0 + wx * 64 + j * 16 + lc;
          if (col < Nn) Cr[col] = f2b(acc[i][j][r] * alpha);
          else if (col < Npad) Cr[col] = 0;
        }
      }
    }
  } else {
    float* C = (float*)Cv + blockIdx.y * CsY + blockIdx.z * CsZ;
    #pragma unroll
    for (int i = 0; i < 4; ++i) {
      #pragma unroll
      for (int r = 0; r < 4; ++r) {
        int row = m0 + wy * 64 + i * 16 + quad * 4 + r;
        if (row >= M) continue;
        float* Cr = C + (long)row * ldc;
        #pragma unroll
        for (int j = 0; j < 4; ++j) {
          int col = n0 + wx * 64 + j * 16 + lc;
          if (col < Nn) Cr[col] = acc[i][j][r] * alpha;
        }
      }
    }
  }
}

// ---------------------------------------------------------------------------
// mfma_ctx: fused ctx GEMM. A=Vh[bh] [1024,256], B=P_b[bh] [240,256], K=256.
// Epilogue maps col -> output channel (h-interleaved) in ctx2 [B,N,960] bf16.
// ---------------------------------------------------------------------------
__global__ __launch_bounds__(256) void mfma_ctx(const ushort* __restrict__ V,
                                                const ushort* __restrict__ P,
                                                ushort* __restrict__ ctx2) {
  const int h = blockIdx.y, b = blockIdx.z;
  const ushort* A  = V + (((long)b * H_ + h) * 1024) * 256;
  const ushort* Bm = P + (((long)b * H_ + h) * 240) * 256;

  const int m0 = (blockIdx.x >> 1) * 128;
  const int n0 = (blockIdx.x & 1) * 128;
  const int tid = threadIdx.x;
  const int l = tid & 63, w = tid >> 6;
  const int wy = w >> 1, wx = w & 1;

  __shared__ __align__(16) ushort As[128 * 32];
  __shared__ __align__(16) ushort Bs[128 * 32];

  f32x4 acc[4][4];
  #pragma unroll
  for (int i = 0; i < 4; ++i)
    #pragma unroll
    for (int j = 0; j < 4; ++j) acc[i][j] = (f32x4)0.f;

  const int srow = tid >> 2;
  const int skc  = (tid & 3) * 8;
  int rb0 = n0 + srow;      rb0 = rb0 < 240 ? rb0 : 239;
  int rb1 = n0 + srow + 64; rb1 = rb1 < 240 ? rb1 : 239;
  const ushort* a0 = A  + (long)(m0 + srow) * 256 + skc;
  const ushort* a1 = A  + (long)(m0 + srow + 64) * 256 + skc;
  const ushort* b0 = Bm + (long)rb0 * 256 + skc;
  const ushort* b1 = Bm + (long)rb1 * 256 + skc;
  ushort* lA0 = As + srow * 32 + skc;
  ushort* lA1 = As + (srow + 64) * 32 + skc;
  ushort* lB0 = Bs + srow * 32 + skc;
  ushort* lB1 = Bs + (srow + 64) * 32 + skc;

  const ushort* arp = As + (wy * 64 + (l & 15)) * 32 + (l >> 4) * 8;
  const ushort* brp = Bs + (wx * 64 + (l & 15)) * 32 + (l >> 4) * 8;

  for (int k0 = 0; k0 < 256; k0 += 32) {
    __syncthreads();
    gload16(a0 + k0, lA0);
    gload16(a1 + k0, lA1);
    gload16(b0 + k0, lB0);
    gload16(b1 + k0, lB1);
    __syncthreads();
    bf16x8 af[4], bfr[4];
    #pragma unroll
    for (int i = 0; i < 4; ++i) af[i]  = *(const bf16x8*)(arp + i * 512);
    #pragma unroll
    for (int j = 0; j < 4; ++j) bfr[j] = *(const bf16x8*)(brp + j * 512);
    #pragma unroll
    for (int i = 0; i < 4; ++i)
      #pragma unroll
      for (int j = 0; j < 4; ++j)
        acc[i][j] = __builtin_amdgcn_mfma_f32_16x16x32_bf16(af[i], bfr[j], acc[i][j], 0, 0, 0);
  }

  const int quad = l >> 4, lc = l & 15;
  const int dss[4] = {16, 32, 64, 128};
  const int qf[4]  = {0, 16, 48, 112};
  const int cf[4]  = {0, 64, 192, 448};
  #pragma unroll
  for (int i = 0; i < 4; ++i) {
    #pragma unroll
    for (int r = 0; r < 4; ++r) {
      int row = m0 + wy * 64 + i * 16 + quad * 4 + r;
      ushort* Cr = ctx2 + ((long)b * N_ + row) * 960;
      #pragma unroll
      for (int j = 0; j < 4; ++j) {
        int col = n0 + wx * 64 + j * 16 + lc;
        if (col < 240) {
          int s = col < 16 ? 0 : col < 48 ? 1 : col < 112 ? 2 : 3;
          int chan = cf[s] + h * dss[s] + (col - qf[s]);
          Cr[chan] = f2b(acc[i][j][r]);
        }
      }
    }
  }
}

// ---------------------------------------------------------------------------
// mfma_oproj: grouped out-projection, ONE dispatch for all 4 scales.
// blocks [0,128) s0, [128,256) s1, [256,512) s2, [512,1024) s3.
// C[row, col] = sum_k ctx2[row, coff_s + k] * Wo_b_s[col, k]  (fp32 out)
// ---------------------------------------------------------------------------
__global__ __launch_bounds__(256) void mfma_oproj(const ushort* __restrict__ ctx2,
                                                  const ushort* __restrict__ Wo_b,
                                                  float* __restrict__ out) {
  const int bx = blockIdx.x;
  int s = bx < 128 ? 0 : bx < 256 ? 1 : bx < 512 ? 2 : 3;
  const int sbase[4] = {0, 128, 256, 512};
  const int cs_[4]   = {64, 128, 256, 512};
  const int coff_[4] = {0, 64, 192, 448};
  const int wo_[4]   = {0, 4096, 20480, 86016};
  const long oo_[4]  = {0, 1048576, 3145728, 7340032};
  const int c = cs_[s];
  const int nt = (c + 127) >> 7;
  const int local = bx - sbase[s];
  const int m0 = (local / nt) * 128;
  const int n0 = (local % nt) * 128;

  const ushort* A  = ctx2 + coff_[s];     // lda 960, rows 16384
  const ushort* Bm = Wo_b + wo_[s];       // ldb c, rows c
  float* C = out + oo_[s];                // ldc c
  const int K = c, Nn = c;

  const int tid = threadIdx.x;
  const int l = tid & 63, w = tid >> 6;
  const int wy = w >> 1, wx = w & 1;

  __shared__ __align__(16) ushort As[128 * 32];
  __shared__ __align__(16) ushort Bs[128 * 32];

  f32x4 acc[4][4];
  #pragma unroll
  for (int i = 0; i < 4; ++i)
    #pragma unroll
    for (int j = 0; j < 4; ++j) acc[i][j] = (f32x4)0.f;

  const int srow = tid >> 2;
  const int skc  = (tid & 3) * 8;
  int rb0 = n0 + srow;      rb0 = rb0 < Nn ? rb0 : Nn - 1;
  int rb1 = n0 + srow + 64; rb1 = rb1 < Nn ? rb1 : Nn - 1;
  const ushort* a0 = A  + (long)(m0 + srow) * 960 + skc;
  const ushort* a1 = A  + (long)(m0 + srow + 64) * 960 + skc;
  const ushort* b0 = Bm + (long)rb0 * c + skc;
  const ushort* b1 = Bm + (long)rb1 * c + skc;
  ushort* lA0 = As + srow * 32 + skc;
  ushort* lA1 = As + (srow + 64) * 32 + skc;
  ushort* lB0 = Bs + srow * 32 + skc;
  ushort* lB1 = Bs + (srow + 64) * 32 + skc;

  const ushort* arp = As + (wy * 64 + (l & 15)) * 32 + (l >> 4) * 8;
  const ushort* brp = Bs + (wx * 64 + (l & 15)) * 32 + (l >> 4) * 8;

  for (int k0 = 0; k0 < K; k0 += 32) {
    __syncthreads();
    gload16(a0 + k0, lA0);
    gload16(a1 + k0, lA1);
    gload16(b0 + k0, lB0);
    gload16(b1 + k0, lB1);
    __syncthreads();
    bf16x8 af[4], bfr[4];
    #pragma unroll
    for (int i = 0; i < 4; ++i) af[i]  = *(const bf16x8*)(arp + i * 512);
    #pragma unroll
    for (int j = 0; j < 4; ++j) bfr[j] = *(const bf16x8*)(brp + j * 512);
    #pragma unroll
    for (int i = 0; i < 4; ++i)
      #pragma unroll
      for (int j = 0; j < 4; ++j)
        acc[i][j] = __builtin_amdgcn_mfma_f32_16x16x32_bf16(af[i], bfr[j], acc[i][j], 0, 0, 0);
  }

  const int quad = l >> 4, lc = l & 15;
  #pragma unroll
  for (int i = 0; i < 4; ++i) {
    #pragma unroll
    for (int r = 0; r < 4; ++r) {
      int row = m0 + wy * 64 + i * 16 + quad * 4 + r;
      float* Cr = C + (long)row * c;
      #pragma unroll
      for (int j = 0; j < 4; ++j) {
        int col = n0 + wx * 64 + j * 16 + lc;
        if (col < Nn) Cr[col] = acc[i][j][r];
      }
    }
  }
}

// ---------------------------------------------------------------------------
// in_stats: per (bh, scale) mean/rstd over the d*240 slice (float4 reads).
// ---------------------------------------------------------------------------
__global__ __launch_bounds__(256) void in_stats(const float* __restrict__ sc,
                                                float* __restrict__ stats) {
  const int doffs[4] = {0, 16, 48, 112};
  const int dss[4]   = {16, 32, 64, 128};
  const int bh = blockIdx.x, sidx = blockIdx.y;
  const float4* S4 = (const float4*)(sc + (long)bh * SC_ + doffs[sidx] * D240);
  const int n4 = dss[sidx] * 60;

  float s = 0.f, s2 = 0.f;
  for (int i = threadIdx.x; i < n4; i += 256) {
    float4 v = S4[i];
    s  += v.x + v.y + v.z + v.w;
    s2 += v.x * v.x + v.y * v.y + v.z * v.z + v.w * v.w;
  }
  #pragma unroll
  for (int o = 32; o > 0; o >>= 1) { s += __shfl_down(s, o); s2 += __shfl_down(s2, o); }

  __shared__ float wsum[4], wsum2[4];
  const int wave = threadIdx.x >> 6, lane = threadIdx.x & 63;
  if (lane == 0) { wsum[wave] = s; wsum2[wave] = s2; }
  __syncthreads();
  if (threadIdx.x == 0) {
    float n = (float)(n4 * 4);
    float ts = wsum[0] + wsum[1] + wsum[2] + wsum[3];
    float ts2 = wsum2[0] + wsum2[1] + wsum2[2] + wsum2[3];
    float mean = ts / n;
    float var = ts2 / n - mean * mean;
    stats[(bh * 4 + sidx) * 2]     = mean;
    stats[(bh * 4 + sidx) * 2 + 1] = rsqrtf(var + 1e-5f);
  }
}

// ---------------------------------------------------------------------------
// sm_apply: one wave per row. Normalize + softmax -> bf16 P. grid (60, 64).
// ---------------------------------------------------------------------------
__global__ __launch_bounds__(256) void sm_apply(const float* __restrict__ sc,
                                                const float* __restrict__ stats,
                                                ushort* __restrict__ P) {
  const int bh = blockIdx.y;
  const int row = blockIdx.x * 4 + (threadIdx.x >> 6);
  const int lane = threadIdx.x & 63;
  const int s = row < 16 ? 0 : row < 48 ? 1 : row < 112 ? 2 : 3;
  const float mean = stats[(bh * 4 + s) * 2];
  const float rstd = stats[(bh * 4 + s) * 2 + 1];
  const float* r = sc + (long)bh * SC_ + (long)row * D240;
  ushort* p = P + ((long)bh * D240 + row) * 256;

  float v[4];
  float mx = -1e30f;
  #pragma unroll
  for (int j = 0; j < 4; ++j) {
    int c = lane + j * 64;
    v[j] = (c < D240) ? (r[c] - mean) * rstd : -1e30f;
    mx = fmaxf(mx, v[j]);
  }
  #pragma unroll
  for (int o = 32; o > 0; o >>= 1) mx = fmaxf(mx, __shfl_xor(mx, o));
  float sum = 0.f;
  #pragma unroll
  for (int j = 0; j < 4; ++j) {
    int c = lane + j * 64;
    v[j] = (c < D240) ? __expf(v[j] - mx) : 0.f;
    sum += v[j];
  }
  #pragma unroll
  for (int o = 32; o > 0; o >>= 1) sum += __shfl_xor(sum, o);
  float inv = 1.f / sum;
  #pragma unroll
  for (int j = 0; j < 4; ++j) {
    int c = lane + j * 64;
    p[c] = (c < D240) ? f2b(v[j] * inv) : (ushort)0;
  }
}

// ---------------------------------------------------------------------------
// launch
// ---------------------------------------------------------------------------
extern "C" void kernel_launch(void* const* d_in, const int* in_sizes, int n_in,
                              void* d_out, int out_size, void* d_ws, size_t ws_size,
                              hipStream_t stream) {
  const float* emb[4] = {(const float*)d_in[0], (const float*)d_in[1],
                         (const float*)d_in[2], (const float*)d_in[3]};
  const float* emb_all = (const float*)d_in[4];
  const float* Wq[4] = {(const float*)d_in[5], (const float*)d_in[6],
                        (const float*)d_in[7], (const float*)d_in[8]};
  const float* Wk = (const float*)d_in[9];
  const float* Wv = (const float*)d_in[10];
  const float* Wo[4] = {(const float*)d_in[11], (const float*)d_in[12],
                        (const float*)d_in[13], (const float*)d_in[14]};
  float* out = (float*)d_out;
  float* sc  = (float*)d_out;   // fp32 scores scratch in out buffer (dead before out-proj)

  // ws layout (ushort offsets), ~165 MB total:
  ushort* wsb     = (ushort*)d_ws;
  ushort* heads_b = wsb;               // [B,H,N,256] -> dead after K/V proj
  ushort* ctx2    = wsb;               // [B,N,960]   (aliases heads_b)
  ushort* emb_h   = wsb + 16777216;    // [B,H,N,256] -> dead after Q-proj
  ushort* P_b     = wsb + 16777216;    // [64,240,256] (aliases emb_h)
  ushort* Q_T     = wsb + 33554432;    // [B,H,240,1024]
  ushort* Kh_T    = wsb + 49283072;    // [B,H,240,1024]
  ushort* Vh      = wsb + 65011712;    // [B,H,1024,256]
  ushort* wts     = wsb + 81788928;    // 716800: Wk_b|Wv_b|Wq_bd|Wo_b
  ushort* Wk_b  = wts;
  ushort* Wv_b  = wts + 61440;
  ushort* Wq_bd = wts + 122880;
  ushort* Wo_b  = wts + 368640;
  float*  stats = (float*)(wsb + 82505728);   // [64][4][2] fp32

  const long sbh256 = 1024L * 256;
  const float alpha_s = 1.0f / sqrtf(960.0f);

  conv_inputs<<<dim3(B_ * N_), 256, 0, stream>>>(emb_all, emb[0], emb[1], emb[2], emb[3],
                                                 heads_b, emb_h);
  conv_weights<<<dim3(2800), 256, 0, stream>>>(Wk, Wv, Wq[0], Wq[1], Wq[2], Wq[3],
                                               Wo[0], Wo[1], Wo[2], Wo[3], wts);

  // K-proj (transposed): Kh_T[bh][e][n] = sum_d Wk[e,d]*heads[bh,n,d]
  mfma_abT<<<dim3(16, 64, 1), 256, 0, stream>>>(
      Wk_b, 256, 0, 0,
      heads_b, 256, sbh256, 0,
      Kh_T, 1024, 240L * 1024, 0,
      240, 1024, 1024, 256, 1.f, 1, 8);

  // V-proj: Vh[bh][n][e], e-pad to 256 zeroed
  mfma_abT<<<dim3(16, 64, 1), 256, 0, stream>>>(
      heads_b, 256, sbh256, 0,
      Wv_b, 256, 0, 0,
      Vh, 256, sbh256, 0,
      1024, 240, 256, 256, 1.f, 1, 2);

  // Q-proj fused across scales (block-diag weights): Q_T[b,h,r,n]
  mfma_abT<<<dim3(16, H_, B_), 256, 0, stream>>>(
      Wq_bd, 256, 240L * 256, 0,
      emb_h, 256, sbh256, (long)H_ * sbh256,
      Q_T, 1024, 240L * 1024, 4L * 240 * 1024,
      240, 1024, 1024, 256, 1.f, 1, 8);

  // fused scores: sc[bh][r][k] = alpha * sum_n Q_T[bh,r,n]*Kh_T[bh,k,n]  (fp32)
  mfma_abT<<<dim3(4, 64, 1), 256, 0, stream>>>(
      Q_T, 1024, 240L * 1024, 0,
      Kh_T, 1024, 240L * 1024, 0,
      sc, 240, (long)SC_, 0,
      240, 240, 240, 1024, alpha_s, 0, 2);

  // InstanceNorm stats + softmax apply -> bf16 probs
  in_stats<<<dim3(64, 4), 256, 0, stream>>>(sc, stats);
  sm_apply<<<dim3(60, 64), 256, 0, stream>>>(sc, stats, P_b);

  // fused ctx: ctx2[b,n,chan(col,h)] = sum_k Vh[bh,n,k]*P[bh,col,k]
  mfma_ctx<<<dim3(16, H_, B_), 256, 0, stream>>>(Vh, P_b, ctx2);

  // grouped out-proj: one dispatch, all four scales
  mfma_oproj<<<dim3(1024), 256, 0, stream>>>(ctx2, Wo_b, out);
}

// Round 6
// 349.705 us; speedup vs baseline: 5.4460x; 1.0498x over previous
//
#include <hip/hip_runtime.h>
#include <hip/hip_bf16.h>
#include <math.h>

#define B_   16
#define N_   1024
#define H_   4
#define D240 240
#define SC_  57600   // 240*240

typedef unsigned short ushort;
typedef __attribute__((ext_vector_type(8))) short bf16x8;
typedef __attribute__((ext_vector_type(8))) unsigned short u16x8;
typedef __attribute__((ext_vector_type(4))) float f32x4;

__device__ __forceinline__ ushort f2b(float v) {
  __hip_bfloat16 h = __float2bfloat16(v);
  return *reinterpret_cast<ushort*>(&h);
}

__device__ __forceinline__ void gload16(const void* g, void* s) {
  __builtin_amdgcn_global_load_lds((const __attribute__((address_space(1))) void*)g,
                                   (__attribute__((address_space(3))) void*)s, 16, 0, 0);
}

// ---------------------------------------------------------------------------
// conv_inputs v3: 2048 blocks x 8 rows. Per-thread segment/base math hoisted.
// thread t: which=t>>7 (0 heads<-emb_all, 1 embh<-emb1..4), h=(t&127)>>5,
// k0=((t&127)&31)*8. 2x float4 load + 1x 16B store per row.
// ---------------------------------------------------------------------------
__global__ __launch_bounds__(256) void conv_inputs(const float* __restrict__ emb_all,
                                                   const float* __restrict__ e1,
                                                   const float* __restrict__ e2,
                                                   const float* __restrict__ e3,
                                                   const float* __restrict__ e4,
                                                   ushort* __restrict__ heads,
                                                   ushort* __restrict__ embh) {
  const int t = threadIdx.x;
  const int which = t >> 7;
  const int gg = t & 127;
  const int h = gg >> 5;
  const int k0 = (gg & 31) * 8;
  const bool active = (k0 < 240);

  const float* base;
  int stride;
  long soff;
  if (which == 0) {
    base = emb_all; stride = 960;
    if (k0 < 16)       soff = h * 16 + k0;
    else if (k0 < 48)  soff = 64  + h * 32  + (k0 - 16);
    else if (k0 < 112) soff = 192 + h * 64  + (k0 - 48);
    else               soff = 448 + h * 128 + (k0 - 112);
  } else {
    if (k0 < 16)       { base = e1; stride = 64;  soff = h * 16  + k0; }
    else if (k0 < 48)  { base = e2; stride = 128; soff = h * 32  + (k0 - 16); }
    else if (k0 < 112) { base = e3; stride = 256; soff = h * 64  + (k0 - 48); }
    else               { base = e4; stride = 512; soff = h * 128 + (k0 - 112); }
  }
  ushort* dbase = which ? embh : heads;

  #pragma unroll
  for (int i = 0; i < 8; ++i) {
    const int bn = blockIdx.x * 8 + i;
    const int b = bn >> 10, n = bn & 1023;
    float4 p0 = {0.f, 0.f, 0.f, 0.f}, p1 = {0.f, 0.f, 0.f, 0.f};
    if (active) {
      const float* s = base + (long)bn * stride + soff;
      p0 = *(const float4*)s;
      p1 = *(const float4*)(s + 4);
    }
    u16x8 w;
    w[0] = f2b(p0.x); w[1] = f2b(p0.y); w[2] = f2b(p0.z); w[3] = f2b(p0.w);
    w[4] = f2b(p1.x); w[5] = f2b(p1.y); w[6] = f2b(p1.z); w[7] = f2b(p1.w);
    *(u16x8*)(dbase + (((long)b * H_ + h) * N_ + n) * 256 + k0) = w;
  }
}

// ---------------------------------------------------------------------------
// conv_weights: Wk_b | Wv_b | Wq_bd (block-diag per head) | Wo_b (col-permuted)
// ---------------------------------------------------------------------------
__global__ __launch_bounds__(256) void conv_weights(
    const float* __restrict__ Wk, const float* __restrict__ Wv,
    const float* __restrict__ q1, const float* __restrict__ q2,
    const float* __restrict__ q3, const float* __restrict__ q4,
    const float* __restrict__ o1, const float* __restrict__ o2,
    const float* __restrict__ o3, const float* __restrict__ o4,
    ushort* __restrict__ wts) {
  long i = (long)blockIdx.x * 256 + threadIdx.x;
  if (i >= 716800) return;
  float v = 0.f;
  if (i < 122880) {
    const float* src = (i < 61440) ? Wk : Wv;
    long j = (i < 61440) ? i : i - 61440;
    int r = j / 256, k = j % 256;
    if (k < 240) v = src[(long)r * 240 + k];
  } else if (i < 368640) {
    long j = i - 122880;
    int h = j / 61440; int rem = j % 61440;
    int r = rem / 256, k = rem % 256;
    int s = r < 16 ? 0 : r < 48 ? 1 : r < 112 ? 2 : 3;
    const int dss[4] = {16, 32, 64, 128};
    const int qf[4]  = {0, 16, 48, 112};
    const float* qs[4] = {q1, q2, q3, q4};
    int d = dss[s], off = qf[s];
    if (k >= off && k < off + d)
      v = qs[s][((long)(h * d + (r - off))) * d + (k - off)];
  } else {
    long j = i - 368640;
    int s = j < 4096 ? 0 : j < 20480 ? 1 : j < 86016 ? 2 : 3;
    const long base[4] = {0, 4096, 20480, 86016};
    const int cs[4] = {64, 128, 256, 512};
    const float* os[4] = {o1, o2, o3, o4};
    long rem = j - base[s];
    int c = cs[s], d = c >> 2;
    int e = rem / c, kk = rem % c;
    v = os[s][(long)e * c + (kk % d) * 4 + kk / d];
  }
  wts[i] = f2b(v);
}

// ---------------------------------------------------------------------------
// Shared GEMM core (bf16 out, alpha=1): C[m,n] = sum_k A[m,k]*B[n,k].
// 128x128 tile, BK=32, 4 waves 2x2, 16x16x32 MFMA. Row-clamped staging.
// ---------------------------------------------------------------------------
__device__ __forceinline__ void gemm_core_b16(
    ushort* As, ushort* Bs,
    const ushort* __restrict__ A, long lda,
    const ushort* __restrict__ Bm, long ldb,
    ushort* __restrict__ C, long ldc,
    int M, int Nn, int Npad, int K, int m0, int n0)
{
  const int tid = threadIdx.x;
  const int l = tid & 63, w = tid >> 6;
  const int wy = w >> 1, wx = w & 1;

  f32x4 acc[4][4];
  #pragma unroll
  for (int i = 0; i < 4; ++i)
    #pragma unroll
    for (int j = 0; j < 4; ++j) acc[i][j] = (f32x4)0.f;

  const int srow = tid >> 2;
  const int skc  = (tid & 3) * 8;
  int ra0 = m0 + srow;      ra0 = ra0 < M  ? ra0 : M - 1;
  int ra1 = m0 + srow + 64; ra1 = ra1 < M  ? ra1 : M - 1;
  int rb0 = n0 + srow;      rb0 = rb0 < Nn ? rb0 : Nn - 1;
  int rb1 = n0 + srow + 64; rb1 = rb1 < Nn ? rb1 : Nn - 1;
  const ushort* a0 = A  + (long)ra0 * lda + skc;
  const ushort* a1 = A  + (long)ra1 * lda + skc;
  const ushort* b0 = Bm + (long)rb0 * ldb + skc;
  const ushort* b1 = Bm + (long)rb1 * ldb + skc;
  ushort* lA0 = As + srow * 32 + skc;
  ushort* lA1 = As + (srow + 64) * 32 + skc;
  ushort* lB0 = Bs + srow * 32 + skc;
  ushort* lB1 = Bs + (srow + 64) * 32 + skc;

  const ushort* arp = As + (wy * 64 + (l & 15)) * 32 + (l >> 4) * 8;
  const ushort* brp = Bs + (wx * 64 + (l & 15)) * 32 + (l >> 4) * 8;

  for (int k0 = 0; k0 < K; k0 += 32) {
    __syncthreads();
    gload16(a0 + k0, lA0);
    gload16(a1 + k0, lA1);
    gload16(b0 + k0, lB0);
    gload16(b1 + k0, lB1);
    __syncthreads();
    bf16x8 af[4], bfr[4];
    #pragma unroll
    for (int i = 0; i < 4; ++i) af[i]  = *(const bf16x8*)(arp + i * 512);
    #pragma unroll
    for (int j = 0; j < 4; ++j) bfr[j] = *(const bf16x8*)(brp + j * 512);
    #pragma unroll
    for (int i = 0; i < 4; ++i)
      #pragma unroll
      for (int j = 0; j < 4; ++j)
        acc[i][j] = __builtin_amdgcn_mfma_f32_16x16x32_bf16(af[i], bfr[j], acc[i][j], 0, 0, 0);
  }

  const int quad = l >> 4, lc = l & 15;
  #pragma unroll
  for (int i = 0; i < 4; ++i) {
    #pragma unroll
    for (int r = 0; r < 4; ++r) {
      int row = m0 + wy * 64 + i * 16 + quad * 4 + r;
      if (row >= M) continue;
      ushort* Cr = C + (long)row * ldc;
      #pragma unroll
      for (int j = 0; j < 4; ++j) {
        int col = n0 + wx * 64 + j * 16 + lc;
        if (col < Nn) Cr[col] = f2b(acc[i][j][r]);
        else if (col < Npad) Cr[col] = 0;
      }
    }
  }
}

// ---------------------------------------------------------------------------
// mfma_proj: K-proj + V-proj + Q-proj in ONE dispatch (3072 blocks).
// [0,1024): Kh_T[bh][e][n]  = sum_d Wk[e,d]   * heads[bh,n,d]   (M=240,N=1024)
// [1024,2048): Vh[bh][n][e] = sum_d heads[bh,n,d] * Wv[e,d]     (M=1024,N=240)
// [2048,3072): Q_T[bh][r][n]= sum_d Wq_bd[h][r,d] * emb_h[bh,n,d]
// ---------------------------------------------------------------------------
__global__ __launch_bounds__(256) void mfma_proj(
    const ushort* __restrict__ heads_b, const ushort* __restrict__ emb_h,
    const ushort* __restrict__ Wk_b, const ushort* __restrict__ Wv_b,
    const ushort* __restrict__ Wq_bd,
    ushort* __restrict__ Kh_T, ushort* __restrict__ Vh, ushort* __restrict__ Q_T)
{
  __shared__ __align__(16) ushort As[128 * 32];
  __shared__ __align__(16) ushort Bs[128 * 32];
  const int bx = blockIdx.x;
  const long sbh = 1024L * 256;

  if (bx < 1024) {
    const int bh = bx >> 4, t = bx & 15;
    gemm_core_b16(As, Bs,
                  Wk_b, 256,
                  heads_b + (long)bh * sbh, 256,
                  Kh_T + (long)bh * 240 * 1024, 1024,
                  240, 1024, 1024, 256, (t >> 3) * 128, (t & 7) * 128);
  } else if (bx < 2048) {
    const int local = bx - 1024;
    const int bh = local >> 4, t = local & 15;
    gemm_core_b16(As, Bs,
                  heads_b + (long)bh * sbh, 256,
                  Wv_b, 256,
                  Vh + (long)bh * sbh, 256,
                  1024, 240, 256, 256, (t >> 1) * 128, (t & 1) * 128);
  } else {
    const int local = bx - 2048;
    const int bh = local >> 4, t = local & 15;
    const int h = bh & 3;
    gemm_core_b16(As, Bs,
                  Wq_bd + h * 61440, 256,
                  emb_h + (long)bh * sbh, 256,
                  Q_T + (long)bh * 240 * 1024, 1024,
                  240, 1024, 1024, 256, (t >> 3) * 128, (t & 7) * 128);
  }
}

// ---------------------------------------------------------------------------
// MFMA GEMM (generic, fp32/bf16 out) — used for scores (split-K via grid.z).
// ---------------------------------------------------------------------------
__global__ __launch_bounds__(256) void mfma_abT(
    const ushort* __restrict__ A, long lda, long AsY, long AsZ,
    const ushort* __restrict__ Bm, long ldb, long BsY, long BsZ,
    void* __restrict__ Cv, long ldc, long CsY, long CsZ,
    int M, int Nn, int Npad, int K, float alpha, int c_bf16, int tilesN)
{
  A  += blockIdx.y * AsY + blockIdx.z * AsZ;
  Bm += blockIdx.y * BsY + blockIdx.z * BsZ;

  const int m0 = (blockIdx.x / tilesN) * 128;
  const int n0 = (blockIdx.x % tilesN) * 128;
  const int tid = threadIdx.x;
  const int l = tid & 63, w = tid >> 6;
  const int wy = w >> 1, wx = w & 1;

  __shared__ __align__(16) ushort As[128 * 32];
  __shared__ __align__(16) ushort Bs[128 * 32];

  f32x4 acc[4][4];
  #pragma unroll
  for (int i = 0; i < 4; ++i)
    #pragma unroll
    for (int j = 0; j < 4; ++j) acc[i][j] = (f32x4)0.f;

  const int srow = tid >> 2;
  const int skc  = (tid & 3) * 8;
  int ra0 = m0 + srow;      ra0 = ra0 < M  ? ra0 : M - 1;
  int ra1 = m0 + srow + 64; ra1 = ra1 < M  ? ra1 : M - 1;
  int rb0 = n0 + srow;      rb0 = rb0 < Nn ? rb0 : Nn - 1;
  int rb1 = n0 + srow + 64; rb1 = rb1 < Nn ? rb1 : Nn - 1;
  const ushort* a0 = A  + (long)ra0 * lda + skc;
  const ushort* a1 = A  + (long)ra1 * lda + skc;
  const ushort* b0 = Bm + (long)rb0 * ldb + skc;
  const ushort* b1 = Bm + (long)rb1 * ldb + skc;
  ushort* lA0 = As + srow * 32 + skc;
  ushort* lA1 = As + (srow + 64) * 32 + skc;
  ushort* lB0 = Bs + srow * 32 + skc;
  ushort* lB1 = Bs + (srow + 64) * 32 + skc;

  const ushort* arp = As + (wy * 64 + (l & 15)) * 32 + (l >> 4) * 8;
  const ushort* brp = Bs + (wx * 64 + (l & 15)) * 32 + (l >> 4) * 8;

  for (int k0 = 0; k0 < K; k0 += 32) {
    __syncthreads();
    gload16(a0 + k0, lA0);
    gload16(a1 + k0, lA1);
    gload16(b0 + k0, lB0);
    gload16(b1 + k0, lB1);
    __syncthreads();
    bf16x8 af[4], bfr[4];
    #pragma unroll
    for (int i = 0; i < 4; ++i) af[i]  = *(const bf16x8*)(arp + i * 512);
    #pragma unroll
    for (int j = 0; j < 4; ++j) bfr[j] = *(const bf16x8*)(brp + j * 512);
    #pragma unroll
    for (int i = 0; i < 4; ++i)
      #pragma unroll
      for (int j = 0; j < 4; ++j)
        acc[i][j] = __builtin_amdgcn_mfma_f32_16x16x32_bf16(af[i], bfr[j], acc[i][j], 0, 0, 0);
  }

  const int quad = l >> 4, lc = l & 15;
  if (c_bf16) {
    ushort* C = (ushort*)Cv + blockIdx.y * CsY + blockIdx.z * CsZ;
    #pragma unroll
    for (int i = 0; i < 4; ++i) {
      #pragma unroll
      for (int r = 0; r < 4; ++r) {
        int row = m0 + wy * 64 + i * 16 + quad * 4 + r;
        if (row >= M) continue;
        ushort* Cr = C + (long)row * ldc;
        #pragma unroll
        for (int j = 0; j < 4; ++j) {
          int col = n0 + wx * 64 + j * 16 + lc;
          if (col < Nn) Cr[col] = f2b(acc[i][j][r] * alpha);
          else if (col < Npad) Cr[col] = 0;
        }
      }
    }
  } else {
    float* C = (float*)Cv + blockIdx.y * CsY + blockIdx.z * CsZ;
    #pragma unroll
    for (int i = 0; i < 4; ++i) {
      #pragma unroll
      for (int r = 0; r < 4; ++r) {
        int row = m0 + wy * 64 + i * 16 + quad * 4 + r;
        if (row >= M) continue;
        float* Cr = C + (long)row * ldc;
        #pragma unroll
        for (int j = 0; j < 4; ++j) {
          int col = n0 + wx * 64 + j * 16 + lc;
          if (col < Nn) Cr[col] = acc[i][j][r] * alpha;
        }
      }
    }
  }
}

// ---------------------------------------------------------------------------
// mfma_ctx: fused ctx GEMM. A=Vh[bh] [1024,256], B=P_b[bh] [240,256], K=256.
// Epilogue maps col -> h-interleaved channel in ctx2 [B,N,960] bf16.
// ---------------------------------------------------------------------------
__global__ __launch_bounds__(256) void mfma_ctx(const ushort* __restrict__ V,
                                                const ushort* __restrict__ P,
                                                ushort* __restrict__ ctx2) {
  const int h = blockIdx.y, b = blockIdx.z;
  const ushort* A  = V + (((long)b * H_ + h) * 1024) * 256;
  const ushort* Bm = P + (((long)b * H_ + h) * 240) * 256;

  const int m0 = (blockIdx.x >> 1) * 128;
  const int n0 = (blockIdx.x & 1) * 128;
  const int tid = threadIdx.x;
  const int l = tid & 63, w = tid >> 6;
  const int wy = w >> 1, wx = w & 1;

  __shared__ __align__(16) ushort As[128 * 32];
  __shared__ __align__(16) ushort Bs[128 * 32];

  f32x4 acc[4][4];
  #pragma unroll
  for (int i = 0; i < 4; ++i)
    #pragma unroll
    for (int j = 0; j < 4; ++j) acc[i][j] = (f32x4)0.f;

  const int srow = tid >> 2;
  const int skc  = (tid & 3) * 8;
  int rb0 = n0 + srow;      rb0 = rb0 < 240 ? rb0 : 239;
  int rb1 = n0 + srow + 64; rb1 = rb1 < 240 ? rb1 : 239;
  const ushort* a0 = A  + (long)(m0 + srow) * 256 + skc;
  const ushort* a1 = A  + (long)(m0 + srow + 64) * 256 + skc;
  const ushort* b0 = Bm + (long)rb0 * 256 + skc;
  const ushort* b1 = Bm + (long)rb1 * 256 + skc;
  ushort* lA0 = As + srow * 32 + skc;
  ushort* lA1 = As + (srow + 64) * 32 + skc;
  ushort* lB0 = Bs + srow * 32 + skc;
  ushort* lB1 = Bs + (srow + 64) * 32 + skc;

  const ushort* arp = As + (wy * 64 + (l & 15)) * 32 + (l >> 4) * 8;
  const ushort* brp = Bs + (wx * 64 + (l & 15)) * 32 + (l >> 4) * 8;

  for (int k0 = 0; k0 < 256; k0 += 32) {
    __syncthreads();
    gload16(a0 + k0, lA0);
    gload16(a1 + k0, lA1);
    gload16(b0 + k0, lB0);
    gload16(b1 + k0, lB1);
    __syncthreads();
    bf16x8 af[4], bfr[4];
    #pragma unroll
    for (int i = 0; i < 4; ++i) af[i]  = *(const bf16x8*)(arp + i * 512);
    #pragma unroll
    for (int j = 0; j < 4; ++j) bfr[j] = *(const bf16x8*)(brp + j * 512);
    #pragma unroll
    for (int i = 0; i < 4; ++i)
      #pragma unroll
      for (int j = 0; j < 4; ++j)
        acc[i][j] = __builtin_amdgcn_mfma_f32_16x16x32_bf16(af[i], bfr[j], acc[i][j], 0, 0, 0);
  }

  const int quad = l >> 4, lc = l & 15;
  const int dss[4] = {16, 32, 64, 128};
  const int qf[4]  = {0, 16, 48, 112};
  const int cf[4]  = {0, 64, 192, 448};
  #pragma unroll
  for (int i = 0; i < 4; ++i) {
    #pragma unroll
    for (int r = 0; r < 4; ++r) {
      int row = m0 + wy * 64 + i * 16 + quad * 4 + r;
      ushort* Cr = ctx2 + ((long)b * N_ + row) * 960;
      #pragma unroll
      for (int j = 0; j < 4; ++j) {
        int col = n0 + wx * 64 + j * 16 + lc;
        if (col < 240) {
          int s = col < 16 ? 0 : col < 48 ? 1 : col < 112 ? 2 : 3;
          int chan = cf[s] + h * dss[s] + (col - qf[s]);
          Cr[chan] = f2b(acc[i][j][r]);
        }
      }
    }
  }
}

// ---------------------------------------------------------------------------
// mfma_oproj: grouped out-projection, one dispatch for all 4 scales.
// ---------------------------------------------------------------------------
__global__ __launch_bounds__(256) void mfma_oproj(const ushort* __restrict__ ctx2,
                                                  const ushort* __restrict__ Wo_b,
                                                  float* __restrict__ out) {
  const int bx = blockIdx.x;
  int s = bx < 128 ? 0 : bx < 256 ? 1 : bx < 512 ? 2 : 3;
  const int sbase[4] = {0, 128, 256, 512};
  const int cs_[4]   = {64, 128, 256, 512};
  const int coff_[4] = {0, 64, 192, 448};
  const int wo_[4]   = {0, 4096, 20480, 86016};
  const long oo_[4]  = {0, 1048576, 3145728, 7340032};
  const int c = cs_[s];
  const int nt = (c + 127) >> 7;
  const int local = bx - sbase[s];
  const int m0 = (local / nt) * 128;
  const int n0 = (local % nt) * 128;

  const ushort* A  = ctx2 + coff_[s];
  const ushort* Bm = Wo_b + wo_[s];
  float* C = out + oo_[s];
  const int K = c, Nn = c;

  const int tid = threadIdx.x;
  const int l = tid & 63, w = tid >> 6;
  const int wy = w >> 1, wx = w & 1;

  __shared__ __align__(16) ushort As[128 * 32];
  __shared__ __align__(16) ushort Bs[128 * 32];

  f32x4 acc[4][4];
  #pragma unroll
  for (int i = 0; i < 4; ++i)
    #pragma unroll
    for (int j = 0; j < 4; ++j) acc[i][j] = (f32x4)0.f;

  const int srow = tid >> 2;
  const int skc  = (tid & 3) * 8;
  int rb0 = n0 + srow;      rb0 = rb0 < Nn ? rb0 : Nn - 1;
  int rb1 = n0 + srow + 64; rb1 = rb1 < Nn ? rb1 : Nn - 1;
  const ushort* a0 = A  + (long)(m0 + srow) * 960 + skc;
  const ushort* a1 = A  + (long)(m0 + srow + 64) * 960 + skc;
  const ushort* b0 = Bm + (long)rb0 * c + skc;
  const ushort* b1 = Bm + (long)rb1 * c + skc;
  ushort* lA0 = As + srow * 32 + skc;
  ushort* lA1 = As + (srow + 64) * 32 + skc;
  ushort* lB0 = Bs + srow * 32 + skc;
  ushort* lB1 = Bs + (srow + 64) * 32 + skc;

  const ushort* arp = As + (wy * 64 + (l & 15)) * 32 + (l >> 4) * 8;
  const ushort* brp = Bs + (wx * 64 + (l & 15)) * 32 + (l >> 4) * 8;

  for (int k0 = 0; k0 < K; k0 += 32) {
    __syncthreads();
    gload16(a0 + k0, lA0);
    gload16(a1 + k0, lA1);
    gload16(b0 + k0, lB0);
    gload16(b1 + k0, lB1);
    __syncthreads();
    bf16x8 af[4], bfr[4];
    #pragma unroll
    for (int i = 0; i < 4; ++i) af[i]  = *(const bf16x8*)(arp + i * 512);
    #pragma unroll
    for (int j = 0; j < 4; ++j) bfr[j] = *(const bf16x8*)(brp + j * 512);
    #pragma unroll
    for (int i = 0; i < 4; ++i)
      #pragma unroll
      for (int j = 0; j < 4; ++j)
        acc[i][j] = __builtin_amdgcn_mfma_f32_16x16x32_bf16(af[i], bfr[j], acc[i][j], 0, 0, 0);
  }

  const int quad = l >> 4, lc = l & 15;
  #pragma unroll
  for (int i = 0; i < 4; ++i) {
    #pragma unroll
    for (int r = 0; r < 4; ++r) {
      int row = m0 + wy * 64 + i * 16 + quad * 4 + r;
      float* Cr = C + (long)row * c;
      #pragma unroll
      for (int j = 0; j < 4; ++j) {
        int col = n0 + wx * 64 + j * 16 + lc;
        if (col < Nn) Cr[col] = acc[i][j][r];
      }
    }
  }
}

// ---------------------------------------------------------------------------
// in_stats: per (bh, scale) mean/rstd over d*240 slice; sums the two split-K
// partial score buffers on the fly.
// ---------------------------------------------------------------------------
__global__ __launch_bounds__(256) void in_stats(const float* __restrict__ sc0,
                                                const float* __restrict__ sc1,
                                                float* __restrict__ stats) {
  const int doffs[4] = {0, 16, 48, 112};
  const int dss[4]   = {16, 32, 64, 128};
  const int bh = blockIdx.x, sidx = blockIdx.y;
  const long base = (long)bh * SC_ + doffs[sidx] * D240;
  const float4* A4 = (const float4*)(sc0 + base);
  const float4* B4 = (const float4*)(sc1 + base);
  const int n4 = dss[sidx] * 60;

  float s = 0.f, s2 = 0.f;
  for (int i = threadIdx.x; i < n4; i += 256) {
    float4 a = A4[i], b = B4[i];
    float x0 = a.x + b.x, x1 = a.y + b.y, x2 = a.z + b.z, x3 = a.w + b.w;
    s  += x0 + x1 + x2 + x3;
    s2 += x0 * x0 + x1 * x1 + x2 * x2 + x3 * x3;
  }
  #pragma unroll
  for (int o = 32; o > 0; o >>= 1) { s += __shfl_down(s, o); s2 += __shfl_down(s2, o); }

  __shared__ float wsum[4], wsum2[4];
  const int wave = threadIdx.x >> 6, lane = threadIdx.x & 63;
  if (lane == 0) { wsum[wave] = s; wsum2[wave] = s2; }
  __syncthreads();
  if (threadIdx.x == 0) {
    float n = (float)(n4 * 4);
    float ts = wsum[0] + wsum[1] + wsum[2] + wsum[3];
    float ts2 = wsum2[0] + wsum2[1] + wsum2[2] + wsum2[3];
    float mean = ts / n;
    float var = ts2 / n - mean * mean;
    stats[(bh * 4 + sidx) * 2]     = mean;
    stats[(bh * 4 + sidx) * 2 + 1] = rsqrtf(var + 1e-5f);
  }
}

// ---------------------------------------------------------------------------
// sm_apply: one wave per row; sums split-K partials, normalize + softmax -> P.
// ---------------------------------------------------------------------------
__global__ __launch_bounds__(256) void sm_apply(const float* __restrict__ sc0,
                                                const float* __restrict__ sc1,
                                                const float* __restrict__ stats,
                                                ushort* __restrict__ P) {
  const int bh = blockIdx.y;
  const int row = blockIdx.x * 4 + (threadIdx.x >> 6);
  const int lane = threadIdx.x & 63;
  const int s = row < 16 ? 0 : row < 48 ? 1 : row < 112 ? 2 : 3;
  const float mean = stats[(bh * 4 + s) * 2];
  const float rstd = stats[(bh * 4 + s) * 2 + 1];
  const long base = (long)bh * SC_ + (long)row * D240;
  const float* r0 = sc0 + base;
  const float* r1 = sc1 + base;
  ushort* p = P + ((long)bh * D240 + row) * 256;

  float v[4];
  float mx = -1e30f;
  #pragma unroll
  for (int j = 0; j < 4; ++j) {
    int c = lane + j * 64;
    v[j] = (c < D240) ? (r0[c] + r1[c] - mean) * rstd : -1e30f;
    mx = fmaxf(mx, v[j]);
  }
  #pragma unroll
  for (int o = 32; o > 0; o >>= 1) mx = fmaxf(mx, __shfl_xor(mx, o));
  float sum = 0.f;
  #pragma unroll
  for (int j = 0; j < 4; ++j) {
    int c = lane + j * 64;
    v[j] = (c < D240) ? __expf(v[j] - mx) : 0.f;
    sum += v[j];
  }
  #pragma unroll
  for (int o = 32; o > 0; o >>= 1) sum += __shfl_xor(sum, o);
  float inv = 1.f / sum;
  #pragma unroll
  for (int j = 0; j < 4; ++j) {
    int c = lane + j * 64;
    p[c] = (c < D240) ? f2b(v[j] * inv) : (ushort)0;
  }
}

// ---------------------------------------------------------------------------
// launch
// ---------------------------------------------------------------------------
extern "C" void kernel_launch(void* const* d_in, const int* in_sizes, int n_in,
                              void* d_out, int out_size, void* d_ws, size_t ws_size,
                              hipStream_t stream) {
  const float* emb[4] = {(const float*)d_in[0], (const float*)d_in[1],
                         (const float*)d_in[2], (const float*)d_in[3]};
  const float* emb_all = (const float*)d_in[4];
  const float* Wq[4] = {(const float*)d_in[5], (const float*)d_in[6],
                        (const float*)d_in[7], (const float*)d_in[8]};
  const float* Wk = (const float*)d_in[9];
  const float* Wv = (const float*)d_in[10];
  const float* Wo[4] = {(const float*)d_in[11], (const float*)d_in[12],
                        (const float*)d_in[13], (const float*)d_in[14]};
  float* out = (float*)d_out;
  float* sc0 = (float*)d_out;                  // split-K partial 0 (3.69M floats)
  float* sc1 = (float*)d_out + 64L * SC_;      // split-K partial 1 (dead before oproj)

  // ws layout (ushort offsets), ~165 MB total:
  ushort* wsb     = (ushort*)d_ws;
  ushort* heads_b = wsb;               // [B,H,N,256] -> dead after proj
  ushort* ctx2    = wsb;               // [B,N,960]   (aliases heads_b)
  ushort* emb_h   = wsb + 16777216;    // [B,H,N,256] -> dead after proj
  ushort* P_b     = wsb + 16777216;    // [64,240,256] (aliases emb_h)
  ushort* Q_T     = wsb + 33554432;    // [B,H,240,1024]
  ushort* Kh_T    = wsb + 49283072;    // [B,H,240,1024]
  ushort* Vh      = wsb + 65011712;    // [B,H,1024,256]
  ushort* wts     = wsb + 81788928;    // 716800: Wk_b|Wv_b|Wq_bd|Wo_b
  ushort* Wk_b  = wts;
  ushort* Wv_b  = wts + 61440;
  ushort* Wq_bd = wts + 122880;
  ushort* Wo_b  = wts + 368640;
  float*  stats = (float*)(wsb + 82505728);   // [64][4][2] fp32

  const float alpha_s = 1.0f / sqrtf(960.0f);

  conv_weights<<<dim3(2800), 256, 0, stream>>>(Wk, Wv, Wq[0], Wq[1], Wq[2], Wq[3],
                                               Wo[0], Wo[1], Wo[2], Wo[3], wts);
  conv_inputs<<<dim3(2048), 256, 0, stream>>>(emb_all, emb[0], emb[1], emb[2], emb[3],
                                              heads_b, emb_h);

  // merged K/V/Q projections
  mfma_proj<<<dim3(3072), 256, 0, stream>>>(heads_b, emb_h, Wk_b, Wv_b, Wq_bd,
                                            Kh_T, Vh, Q_T);

  // fused scores, split-K x2: sc_z[bh][r][k] = alpha * sum_{n in half z} Q_T*Kh_T
  mfma_abT<<<dim3(4, 64, 2), 256, 0, stream>>>(
      Q_T, 1024, 240L * 1024, 512,
      Kh_T, 1024, 240L * 1024, 512,
      sc0, 240, (long)SC_, 64L * SC_,
      240, 240, 240, 512, alpha_s, 0, 2);

  // InstanceNorm stats + softmax apply (summing partials) -> bf16 probs
  in_stats<<<dim3(64, 4), 256, 0, stream>>>(sc0, sc1, stats);
  sm_apply<<<dim3(60, 64), 256, 0, stream>>>(sc0, sc1, stats, P_b);

  // fused ctx: ctx2[b,n,chan(col,h)] = sum_k Vh[bh,n,k]*P[bh,col,k]
  mfma_ctx<<<dim3(16, H_, B_), 256, 0, stream>>>(Vh, P_b, ctx2);

  // grouped out-proj: one dispatch, all four scales
  mfma_oproj<<<dim3(1024), 256, 0, stream>>>(ctx2, Wo_b, out);
}

// Round 7
// 345.465 us; speedup vs baseline: 5.5128x; 1.0123x over previous
//
#include <hip/hip_runtime.h>
#include <hip/hip_bf16.h>
#include <math.h>

#define B_   16
#define N_   1024
#define H_   4
#define D240 240
#define SC_  57600   // 240*240

typedef unsigned short ushort;
typedef __attribute__((ext_vector_type(8))) short bf16x8;
typedef __attribute__((ext_vector_type(8))) unsigned short u16x8;
typedef __attribute__((ext_vector_type(4))) float f32x4;

__device__ __forceinline__ ushort f2b(float v) {
  __hip_bfloat16 h = __float2bfloat16(v);
  return *reinterpret_cast<ushort*>(&h);
}

__device__ __forceinline__ void gload16(const void* g, void* s) {
  __builtin_amdgcn_global_load_lds((const __attribute__((address_space(1))) void*)g,
                                   (__attribute__((address_space(3))) void*)s, 16, 0, 0);
}

// ---------------------------------------------------------------------------
// conv_inputs v4: 4096 blocks x 4 rows, two-phase (batch loads -> stores)
// so all 8 16B loads are in flight before the first use (ILP fix; v3 had
// VGPR=12 -> serialized one-load-at-a-time, 2.1 TB/s).
// thread t: which=t>>7 (0: heads<-emb_all, 1: embh<-emb1..4), h=(t&127)>>5,
// k0=((t&127)&31)*8.
// ---------------------------------------------------------------------------
__global__ __launch_bounds__(256) void conv_inputs(const float* __restrict__ emb_all,
                                                   const float* __restrict__ e1,
                                                   const float* __restrict__ e2,
                                                   const float* __restrict__ e3,
                                                   const float* __restrict__ e4,
                                                   ushort* __restrict__ heads,
                                                   ushort* __restrict__ embh) {
  const int t = threadIdx.x;
  const int which = t >> 7;
  const int gg = t & 127;
  const int h = gg >> 5;
  const int k0 = (gg & 31) * 8;
  const bool active = (k0 < 240);

  const float* base;
  int stride;
  long soff;
  if (which == 0) {
    base = emb_all; stride = 960;
    if (k0 < 16)       soff = h * 16 + k0;
    else if (k0 < 48)  soff = 64  + h * 32  + (k0 - 16);
    else if (k0 < 112) soff = 192 + h * 64  + (k0 - 48);
    else               soff = 448 + h * 128 + (k0 - 112);
  } else {
    if (k0 < 16)       { base = e1; stride = 64;  soff = h * 16  + k0; }
    else if (k0 < 48)  { base = e2; stride = 128; soff = h * 32  + (k0 - 16); }
    else if (k0 < 112) { base = e3; stride = 256; soff = h * 64  + (k0 - 48); }
    else               { base = e4; stride = 512; soff = h * 128 + (k0 - 112); }
  }
  ushort* dbase = which ? embh : heads;
  const int bn0 = blockIdx.x * 4;

  // phase 1: all loads issued back-to-back
  float4 p[4][2];
  #pragma unroll
  for (int i = 0; i < 4; ++i) {
    p[i][0] = make_float4(0.f, 0.f, 0.f, 0.f);
    p[i][1] = make_float4(0.f, 0.f, 0.f, 0.f);
    if (active) {
      const float* s = base + (long)(bn0 + i) * stride + soff;
      p[i][0] = *(const float4*)s;
      p[i][1] = *(const float4*)(s + 4);
    }
  }

  // phase 2: convert + store
  #pragma unroll
  for (int i = 0; i < 4; ++i) {
    const int bn = bn0 + i;
    const int b = bn >> 10, n = bn & 1023;
    u16x8 w;
    w[0] = f2b(p[i][0].x); w[1] = f2b(p[i][0].y);
    w[2] = f2b(p[i][0].z); w[3] = f2b(p[i][0].w);
    w[4] = f2b(p[i][1].x); w[5] = f2b(p[i][1].y);
    w[6] = f2b(p[i][1].z); w[7] = f2b(p[i][1].w);
    *(u16x8*)(dbase + (((long)b * H_ + h) * N_ + n) * 256 + k0) = w;
  }
}

// ---------------------------------------------------------------------------
// conv_weights: Wk_b | Wv_b | Wq_bd (block-diag per head) | Wo_b (col-permuted)
// ---------------------------------------------------------------------------
__global__ __launch_bounds__(256) void conv_weights(
    const float* __restrict__ Wk, const float* __restrict__ Wv,
    const float* __restrict__ q1, const float* __restrict__ q2,
    const float* __restrict__ q3, const float* __restrict__ q4,
    const float* __restrict__ o1, const float* __restrict__ o2,
    const float* __restrict__ o3, const float* __restrict__ o4,
    ushort* __restrict__ wts) {
  long i = (long)blockIdx.x * 256 + threadIdx.x;
  if (i >= 716800) return;
  float v = 0.f;
  if (i < 122880) {
    const float* src = (i < 61440) ? Wk : Wv;
    long j = (i < 61440) ? i : i - 61440;
    int r = j / 256, k = j % 256;
    if (k < 240) v = src[(long)r * 240 + k];
  } else if (i < 368640) {
    long j = i - 122880;
    int h = j / 61440; int rem = j % 61440;
    int r = rem / 256, k = rem % 256;
    int s = r < 16 ? 0 : r < 48 ? 1 : r < 112 ? 2 : 3;
    const int dss[4] = {16, 32, 64, 128};
    const int qf[4]  = {0, 16, 48, 112};
    const float* qs[4] = {q1, q2, q3, q4};
    int d = dss[s], off = qf[s];
    if (k >= off && k < off + d)
      v = qs[s][((long)(h * d + (r - off))) * d + (k - off)];
  } else {
    long j = i - 368640;
    int s = j < 4096 ? 0 : j < 20480 ? 1 : j < 86016 ? 2 : 3;
    const long base[4] = {0, 4096, 20480, 86016};
    const int cs[4] = {64, 128, 256, 512};
    const float* os[4] = {o1, o2, o3, o4};
    long rem = j - base[s];
    int c = cs[s], d = c >> 2;
    int e = rem / c, kk = rem % c;
    v = os[s][(long)e * c + (kk % d) * 4 + kk / d];
  }
  wts[i] = f2b(v);
}

// ---------------------------------------------------------------------------
// Shared GEMM core (bf16 out, alpha=1): C[m,n] = sum_k A[m,k]*B[n,k].
// 128x128 tile, BK=32, 4 waves 2x2, 16x16x32 MFMA. Row-clamped staging.
// ---------------------------------------------------------------------------
__device__ __forceinline__ void gemm_core_b16(
    ushort* As, ushort* Bs,
    const ushort* __restrict__ A, long lda,
    const ushort* __restrict__ Bm, long ldb,
    ushort* __restrict__ C, long ldc,
    int M, int Nn, int Npad, int K, int m0, int n0)
{
  const int tid = threadIdx.x;
  const int l = tid & 63, w = tid >> 6;
  const int wy = w >> 1, wx = w & 1;

  f32x4 acc[4][4];
  #pragma unroll
  for (int i = 0; i < 4; ++i)
    #pragma unroll
    for (int j = 0; j < 4; ++j) acc[i][j] = (f32x4)0.f;

  const int srow = tid >> 2;
  const int skc  = (tid & 3) * 8;
  int ra0 = m0 + srow;      ra0 = ra0 < M  ? ra0 : M - 1;
  int ra1 = m0 + srow + 64; ra1 = ra1 < M  ? ra1 : M - 1;
  int rb0 = n0 + srow;      rb0 = rb0 < Nn ? rb0 : Nn - 1;
  int rb1 = n0 + srow + 64; rb1 = rb1 < Nn ? rb1 : Nn - 1;
  const ushort* a0 = A  + (long)ra0 * lda + skc;
  const ushort* a1 = A  + (long)ra1 * lda + skc;
  const ushort* b0 = Bm + (long)rb0 * ldb + skc;
  const ushort* b1 = Bm + (long)rb1 * ldb + skc;
  ushort* lA0 = As + srow * 32 + skc;
  ushort* lA1 = As + (srow + 64) * 32 + skc;
  ushort* lB0 = Bs + srow * 32 + skc;
  ushort* lB1 = Bs + (srow + 64) * 32 + skc;

  const ushort* arp = As + (wy * 64 + (l & 15)) * 32 + (l >> 4) * 8;
  const ushort* brp = Bs + (wx * 64 + (l & 15)) * 32 + (l >> 4) * 8;

  for (int k0 = 0; k0 < K; k0 += 32) {
    __syncthreads();
    gload16(a0 + k0, lA0);
    gload16(a1 + k0, lA1);
    gload16(b0 + k0, lB0);
    gload16(b1 + k0, lB1);
    __syncthreads();
    bf16x8 af[4], bfr[4];
    #pragma unroll
    for (int i = 0; i < 4; ++i) af[i]  = *(const bf16x8*)(arp + i * 512);
    #pragma unroll
    for (int j = 0; j < 4; ++j) bfr[j] = *(const bf16x8*)(brp + j * 512);
    #pragma unroll
    for (int i = 0; i < 4; ++i)
      #pragma unroll
      for (int j = 0; j < 4; ++j)
        acc[i][j] = __builtin_amdgcn_mfma_f32_16x16x32_bf16(af[i], bfr[j], acc[i][j], 0, 0, 0);
  }

  const int quad = l >> 4, lc = l & 15;
  #pragma unroll
  for (int i = 0; i < 4; ++i) {
    #pragma unroll
    for (int r = 0; r < 4; ++r) {
      int row = m0 + wy * 64 + i * 16 + quad * 4 + r;
      if (row >= M) continue;
      ushort* Cr = C + (long)row * ldc;
      #pragma unroll
      for (int j = 0; j < 4; ++j) {
        int col = n0 + wx * 64 + j * 16 + lc;
        if (col < Nn) Cr[col] = f2b(acc[i][j][r]);
        else if (col < Npad) Cr[col] = 0;
      }
    }
  }
}

// ---------------------------------------------------------------------------
// mfma_proj: K-proj + V-proj + Q-proj in ONE dispatch (3072 blocks).
// ---------------------------------------------------------------------------
__global__ __launch_bounds__(256) void mfma_proj(
    const ushort* __restrict__ heads_b, const ushort* __restrict__ emb_h,
    const ushort* __restrict__ Wk_b, const ushort* __restrict__ Wv_b,
    const ushort* __restrict__ Wq_bd,
    ushort* __restrict__ Kh_T, ushort* __restrict__ Vh, ushort* __restrict__ Q_T)
{
  __shared__ __align__(16) ushort As[128 * 32];
  __shared__ __align__(16) ushort Bs[128 * 32];
  const int bx = blockIdx.x;
  const long sbh = 1024L * 256;

  if (bx < 1024) {
    const int bh = bx >> 4, t = bx & 15;
    gemm_core_b16(As, Bs,
                  Wk_b, 256,
                  heads_b + (long)bh * sbh, 256,
                  Kh_T + (long)bh * 240 * 1024, 1024,
                  240, 1024, 1024, 256, (t >> 3) * 128, (t & 7) * 128);
  } else if (bx < 2048) {
    const int local = bx - 1024;
    const int bh = local >> 4, t = local & 15;
    gemm_core_b16(As, Bs,
                  heads_b + (long)bh * sbh, 256,
                  Wv_b, 256,
                  Vh + (long)bh * sbh, 256,
                  1024, 240, 256, 256, (t >> 1) * 128, (t & 1) * 128);
  } else {
    const int local = bx - 2048;
    const int bh = local >> 4, t = local & 15;
    const int h = bh & 3;
    gemm_core_b16(As, Bs,
                  Wq_bd + h * 61440, 256,
                  emb_h + (long)bh * sbh, 256,
                  Q_T + (long)bh * 240 * 1024, 1024,
                  240, 1024, 1024, 256, (t >> 3) * 128, (t & 7) * 128);
  }
}

// ---------------------------------------------------------------------------
// MFMA GEMM (generic, fp32/bf16 out) — used for scores (split-K via grid.z).
// ---------------------------------------------------------------------------
__global__ __launch_bounds__(256) void mfma_abT(
    const ushort* __restrict__ A, long lda, long AsY, long AsZ,
    const ushort* __restrict__ Bm, long ldb, long BsY, long BsZ,
    void* __restrict__ Cv, long ldc, long CsY, long CsZ,
    int M, int Nn, int Npad, int K, float alpha, int c_bf16, int tilesN)
{
  A  += blockIdx.y * AsY + blockIdx.z * AsZ;
  Bm += blockIdx.y * BsY + blockIdx.z * BsZ;

  const int m0 = (blockIdx.x / tilesN) * 128;
  const int n0 = (blockIdx.x % tilesN) * 128;
  const int tid = threadIdx.x;
  const int l = tid & 63, w = tid >> 6;
  const int wy = w >> 1, wx = w & 1;

  __shared__ __align__(16) ushort As[128 * 32];
  __shared__ __align__(16) ushort Bs[128 * 32];

  f32x4 acc[4][4];
  #pragma unroll
  for (int i = 0; i < 4; ++i)
    #pragma unroll
    for (int j = 0; j < 4; ++j) acc[i][j] = (f32x4)0.f;

  const int srow = tid >> 2;
  const int skc  = (tid & 3) * 8;
  int ra0 = m0 + srow;      ra0 = ra0 < M  ? ra0 : M - 1;
  int ra1 = m0 + srow + 64; ra1 = ra1 < M  ? ra1 : M - 1;
  int rb0 = n0 + srow;      rb0 = rb0 < Nn ? rb0 : Nn - 1;
  int rb1 = n0 + srow + 64; rb1 = rb1 < Nn ? rb1 : Nn - 1;
  const ushort* a0 = A  + (long)ra0 * lda + skc;
  const ushort* a1 = A  + (long)ra1 * lda + skc;
  const ushort* b0 = Bm + (long)rb0 * ldb + skc;
  const ushort* b1 = Bm + (long)rb1 * ldb + skc;
  ushort* lA0 = As + srow * 32 + skc;
  ushort* lA1 = As + (srow + 64) * 32 + skc;
  ushort* lB0 = Bs + srow * 32 + skc;
  ushort* lB1 = Bs + (srow + 64) * 32 + skc;

  const ushort* arp = As + (wy * 64 + (l & 15)) * 32 + (l >> 4) * 8;
  const ushort* brp = Bs + (wx * 64 + (l & 15)) * 32 + (l >> 4) * 8;

  for (int k0 = 0; k0 < K; k0 += 32) {
    __syncthreads();
    gload16(a0 + k0, lA0);
    gload16(a1 + k0, lA1);
    gload16(b0 + k0, lB0);
    gload16(b1 + k0, lB1);
    __syncthreads();
    bf16x8 af[4], bfr[4];
    #pragma unroll
    for (int i = 0; i < 4; ++i) af[i]  = *(const bf16x8*)(arp + i * 512);
    #pragma unroll
    for (int j = 0; j < 4; ++j) bfr[j] = *(const bf16x8*)(brp + j * 512);
    #pragma unroll
    for (int i = 0; i < 4; ++i)
      #pragma unroll
      for (int j = 0; j < 4; ++j)
        acc[i][j] = __builtin_amdgcn_mfma_f32_16x16x32_bf16(af[i], bfr[j], acc[i][j], 0, 0, 0);
  }

  const int quad = l >> 4, lc = l & 15;
  if (c_bf16) {
    ushort* C = (ushort*)Cv + blockIdx.y * CsY + blockIdx.z * CsZ;
    #pragma unroll
    for (int i = 0; i < 4; ++i) {
      #pragma unroll
      for (int r = 0; r < 4; ++r) {
        int row = m0 + wy * 64 + i * 16 + quad * 4 + r;
        if (row >= M) continue;
        ushort* Cr = C + (long)row * ldc;
        #pragma unroll
        for (int j = 0; j < 4; ++j) {
          int col = n0 + wx * 64 + j * 16 + lc;
          if (col < Nn) Cr[col] = f2b(acc[i][j][r] * alpha);
          else if (col < Npad) Cr[col] = 0;
        }
      }
    }
  } else {
    float* C = (float*)Cv + blockIdx.y * CsY + blockIdx.z * CsZ;
    #pragma unroll
    for (int i = 0; i < 4; ++i) {
      #pragma unroll
      for (int r = 0; r < 4; ++r) {
        int row = m0 + wy * 64 + i * 16 + quad * 4 + r;
        if (row >= M) continue;
        float* Cr = C + (long)row * ldc;
        #pragma unroll
        for (int j = 0; j < 4; ++j) {
          int col = n0 + wx * 64 + j * 16 + lc;
          if (col < Nn) Cr[col] = acc[i][j][r] * alpha;
        }
      }
    }
  }
}

// ---------------------------------------------------------------------------
// mfma_ctx: fused ctx GEMM. A=Vh[bh] [1024,256], B=P_b[bh] [240,256], K=256.
// Epilogue maps col -> h-interleaved channel in ctx2 [B,N,960] bf16.
// ---------------------------------------------------------------------------
__global__ __launch_bounds__(256) void mfma_ctx(const ushort* __restrict__ V,
                                                const ushort* __restrict__ P,
                                                ushort* __restrict__ ctx2) {
  const int h = blockIdx.y, b = blockIdx.z;
  const ushort* A  = V + (((long)b * H_ + h) * 1024) * 256;
  const ushort* Bm = P + (((long)b * H_ + h) * 240) * 256;

  const int m0 = (blockIdx.x >> 1) * 128;
  const int n0 = (blockIdx.x & 1) * 128;
  const int tid = threadIdx.x;
  const int l = tid & 63, w = tid >> 6;
  const int wy = w >> 1, wx = w & 1;

  __shared__ __align__(16) ushort As[128 * 32];
  __shared__ __align__(16) ushort Bs[128 * 32];

  f32x4 acc[4][4];
  #pragma unroll
  for (int i = 0; i < 4; ++i)
    #pragma unroll
    for (int j = 0; j < 4; ++j) acc[i][j] = (f32x4)0.f;

  const int srow = tid >> 2;
  const int skc  = (tid & 3) * 8;
  int rb0 = n0 + srow;      rb0 = rb0 < 240 ? rb0 : 239;
  int rb1 = n0 + srow + 64; rb1 = rb1 < 240 ? rb1 : 239;
  const ushort* a0 = A  + (long)(m0 + srow) * 256 + skc;
  const ushort* a1 = A  + (long)(m0 + srow + 64) * 256 + skc;
  const ushort* b0 = Bm + (long)rb0 * 256 + skc;
  const ushort* b1 = Bm + (long)rb1 * 256 + skc;
  ushort* lA0 = As + srow * 32 + skc;
  ushort* lA1 = As + (srow + 64) * 32 + skc;
  ushort* lB0 = Bs + srow * 32 + skc;
  ushort* lB1 = Bs + (srow + 64) * 32 + skc;

  const ushort* arp = As + (wy * 64 + (l & 15)) * 32 + (l >> 4) * 8;
  const ushort* brp = Bs + (wx * 64 + (l & 15)) * 32 + (l >> 4) * 8;

  for (int k0 = 0; k0 < 256; k0 += 32) {
    __syncthreads();
    gload16(a0 + k0, lA0);
    gload16(a1 + k0, lA1);
    gload16(b0 + k0, lB0);
    gload16(b1 + k0, lB1);
    __syncthreads();
    bf16x8 af[4], bfr[4];
    #pragma unroll
    for (int i = 0; i < 4; ++i) af[i]  = *(const bf16x8*)(arp + i * 512);
    #pragma unroll
    for (int j = 0; j < 4; ++j) bfr[j] = *(const bf16x8*)(brp + j * 512);
    #pragma unroll
    for (int i = 0; i < 4; ++i)
      #pragma unroll
      for (int j = 0; j < 4; ++j)
        acc[i][j] = __builtin_amdgcn_mfma_f32_16x16x32_bf16(af[i], bfr[j], acc[i][j], 0, 0, 0);
  }

  const int quad = l >> 4, lc = l & 15;
  const int dss[4] = {16, 32, 64, 128};
  const int qf[4]  = {0, 16, 48, 112};
  const int cf[4]  = {0, 64, 192, 448};
  #pragma unroll
  for (int i = 0; i < 4; ++i) {
    #pragma unroll
    for (int r = 0; r < 4; ++r) {
      int row = m0 + wy * 64 + i * 16 + quad * 4 + r;
      ushort* Cr = ctx2 + ((long)b * N_ + row) * 960;
      #pragma unroll
      for (int j = 0; j < 4; ++j) {
        int col = n0 + wx * 64 + j * 16 + lc;
        if (col < 240) {
          int s = col < 16 ? 0 : col < 48 ? 1 : col < 112 ? 2 : 3;
          int chan = cf[s] + h * dss[s] + (col - qf[s]);
          Cr[chan] = f2b(acc[i][j][r]);
        }
      }
    }
  }
}

// ---------------------------------------------------------------------------
// mfma_oproj: grouped out-projection, one dispatch for all 4 scales.
// ---------------------------------------------------------------------------
__global__ __launch_bounds__(256) void mfma_oproj(const ushort* __restrict__ ctx2,
                                                  const ushort* __restrict__ Wo_b,
                                                  float* __restrict__ out) {
  const int bx = blockIdx.x;
  int s = bx < 128 ? 0 : bx < 256 ? 1 : bx < 512 ? 2 : 3;
  const int sbase[4] = {0, 128, 256, 512};
  const int cs_[4]   = {64, 128, 256, 512};
  const int coff_[4] = {0, 64, 192, 448};
  const int wo_[4]   = {0, 4096, 20480, 86016};
  const long oo_[4]  = {0, 1048576, 3145728, 7340032};
  const int c = cs_[s];
  const int nt = (c + 127) >> 7;
  const int local = bx - sbase[s];
  const int m0 = (local / nt) * 128;
  const int n0 = (local % nt) * 128;

  const ushort* A  = ctx2 + coff_[s];
  const ushort* Bm = Wo_b + wo_[s];
  float* C = out + oo_[s];
  const int K = c, Nn = c;

  const int tid = threadIdx.x;
  const int l = tid & 63, w = tid >> 6;
  const int wy = w >> 1, wx = w & 1;

  __shared__ __align__(16) ushort As[128 * 32];
  __shared__ __align__(16) ushort Bs[128 * 32];

  f32x4 acc[4][4];
  #pragma unroll
  for (int i = 0; i < 4; ++i)
    #pragma unroll
    for (int j = 0; j < 4; ++j) acc[i][j] = (f32x4)0.f;

  const int srow = tid >> 2;
  const int skc  = (tid & 3) * 8;
  int rb0 = n0 + srow;      rb0 = rb0 < Nn ? rb0 : Nn - 1;
  int rb1 = n0 + srow + 64; rb1 = rb1 < Nn ? rb1 : Nn - 1;
  const ushort* a0 = A  + (long)(m0 + srow) * 960 + skc;
  const ushort* a1 = A  + (long)(m0 + srow + 64) * 960 + skc;
  const ushort* b0 = Bm + (long)rb0 * c + skc;
  const ushort* b1 = Bm + (long)rb1 * c + skc;
  ushort* lA0 = As + srow * 32 + skc;
  ushort* lA1 = As + (srow + 64) * 32 + skc;
  ushort* lB0 = Bs + srow * 32 + skc;
  ushort* lB1 = Bs + (srow + 64) * 32 + skc;

  const ushort* arp = As + (wy * 64 + (l & 15)) * 32 + (l >> 4) * 8;
  const ushort* brp = Bs + (wx * 64 + (l & 15)) * 32 + (l >> 4) * 8;

  for (int k0 = 0; k0 < K; k0 += 32) {
    __syncthreads();
    gload16(a0 + k0, lA0);
    gload16(a1 + k0, lA1);
    gload16(b0 + k0, lB0);
    gload16(b1 + k0, lB1);
    __syncthreads();
    bf16x8 af[4], bfr[4];
    #pragma unroll
    for (int i = 0; i < 4; ++i) af[i]  = *(const bf16x8*)(arp + i * 512);
    #pragma unroll
    for (int j = 0; j < 4; ++j) bfr[j] = *(const bf16x8*)(brp + j * 512);
    #pragma unroll
    for (int i = 0; i < 4; ++i)
      #pragma unroll
      for (int j = 0; j < 4; ++j)
        acc[i][j] = __builtin_amdgcn_mfma_f32_16x16x32_bf16(af[i], bfr[j], acc[i][j], 0, 0, 0);
  }

  const int quad = l >> 4, lc = l & 15;
  #pragma unroll
  for (int i = 0; i < 4; ++i) {
    #pragma unroll
    for (int r = 0; r < 4; ++r) {
      int row = m0 + wy * 64 + i * 16 + quad * 4 + r;
      float* Cr = C + (long)row * c;
      #pragma unroll
      for (int j = 0; j < 4; ++j) {
        int col = n0 + wx * 64 + j * 16 + lc;
        if (col < Nn) Cr[col] = acc[i][j][r];
      }
    }
  }
}

// ---------------------------------------------------------------------------
// in_stats: per (bh, scale) mean/rstd over d*240 slice; sums split-K partials.
// ---------------------------------------------------------------------------
__global__ __launch_bounds__(256) void in_stats(const float* __restrict__ sc0,
                                                const float* __restrict__ sc1,
                                                float* __restrict__ stats) {
  const int doffs[4] = {0, 16, 48, 112};
  const int dss[4]   = {16, 32, 64, 128};
  const int bh = blockIdx.x, sidx = blockIdx.y;
  const long base = (long)bh * SC_ + doffs[sidx] * D240;
  const float4* A4 = (const float4*)(sc0 + base);
  const float4* B4 = (const float4*)(sc1 + base);
  const int n4 = dss[sidx] * 60;

  float s = 0.f, s2 = 0.f;
  for (int i = threadIdx.x; i < n4; i += 256) {
    float4 a = A4[i], b = B4[i];
    float x0 = a.x + b.x, x1 = a.y + b.y, x2 = a.z + b.z, x3 = a.w + b.w;
    s  += x0 + x1 + x2 + x3;
    s2 += x0 * x0 + x1 * x1 + x2 * x2 + x3 * x3;
  }
  #pragma unroll
  for (int o = 32; o > 0; o >>= 1) { s += __shfl_down(s, o); s2 += __shfl_down(s2, o); }

  __shared__ float wsum[4], wsum2[4];
  const int wave = threadIdx.x >> 6, lane = threadIdx.x & 63;
  if (lane == 0) { wsum[wave] = s; wsum2[wave] = s2; }
  __syncthreads();
  if (threadIdx.x == 0) {
    float n = (float)(n4 * 4);
    float ts = wsum[0] + wsum[1] + wsum[2] + wsum[3];
    float ts2 = wsum2[0] + wsum2[1] + wsum2[2] + wsum2[3];
    float mean = ts / n;
    float var = ts2 / n - mean * mean;
    stats[(bh * 4 + sidx) * 2]     = mean;
    stats[(bh * 4 + sidx) * 2 + 1] = rsqrtf(var + 1e-5f);
  }
}

// ---------------------------------------------------------------------------
// sm_apply: one wave per row; sums split-K partials, normalize + softmax -> P.
// ---------------------------------------------------------------------------
__global__ __launch_bounds__(256) void sm_apply(const float* __restrict__ sc0,
                                                const float* __restrict__ sc1,
                                                const float* __restrict__ stats,
                                                ushort* __restrict__ P) {
  const int bh = blockIdx.y;
  const int row = blockIdx.x * 4 + (threadIdx.x >> 6);
  const int lane = threadIdx.x & 63;
  const int s = row < 16 ? 0 : row < 48 ? 1 : row < 112 ? 2 : 3;
  const float mean = stats[(bh * 4 + s) * 2];
  const float rstd = stats[(bh * 4 + s) * 2 + 1];
  const long base = (long)bh * SC_ + (long)row * D240;
  const float* r0 = sc0 + base;
  const float* r1 = sc1 + base;
  ushort* p = P + ((long)bh * D240 + row) * 256;

  float v[4];
  float mx = -1e30f;
  #pragma unroll
  for (int j = 0; j < 4; ++j) {
    int c = lane + j * 64;
    v[j] = (c < D240) ? (r0[c] + r1[c] - mean) * rstd : -1e30f;
    mx = fmaxf(mx, v[j]);
  }
  #pragma unroll
  for (int o = 32; o > 0; o >>= 1) mx = fmaxf(mx, __shfl_xor(mx, o));
  float sum = 0.f;
  #pragma unroll
  for (int j = 0; j < 4; ++j) {
    int c = lane + j * 64;
    v[j] = (c < D240) ? __expf(v[j] - mx) : 0.f;
    sum += v[j];
  }
  #pragma unroll
  for (int o = 32; o > 0; o >>= 1) sum += __shfl_xor(sum, o);
  float inv = 1.f / sum;
  #pragma unroll
  for (int j = 0; j < 4; ++j) {
    int c = lane + j * 64;
    p[c] = (c < D240) ? f2b(v[j] * inv) : (ushort)0;
  }
}

// ---------------------------------------------------------------------------
// launch
// ---------------------------------------------------------------------------
extern "C" void kernel_launch(void* const* d_in, const int* in_sizes, int n_in,
                              void* d_out, int out_size, void* d_ws, size_t ws_size,
                              hipStream_t stream) {
  const float* emb[4] = {(const float*)d_in[0], (const float*)d_in[1],
                         (const float*)d_in[2], (const float*)d_in[3]};
  const float* emb_all = (const float*)d_in[4];
  const float* Wq[4] = {(const float*)d_in[5], (const float*)d_in[6],
                        (const float*)d_in[7], (const float*)d_in[8]};
  const float* Wk = (const float*)d_in[9];
  const float* Wv = (const float*)d_in[10];
  const float* Wo[4] = {(const float*)d_in[11], (const float*)d_in[12],
                        (const float*)d_in[13], (const float*)d_in[14]};
  float* out = (float*)d_out;
  float* sc0 = (float*)d_out;                  // split-K partial 0
  float* sc1 = (float*)d_out + 64L * SC_;      // split-K partial 1

  ushort* wsb     = (ushort*)d_ws;
  ushort* heads_b = wsb;               // [B,H,N,256] -> dead after proj
  ushort* ctx2    = wsb;               // [B,N,960]   (aliases heads_b)
  ushort* emb_h   = wsb + 16777216;    // [B,H,N,256] -> dead after proj
  ushort* P_b     = wsb + 16777216;    // [64,240,256] (aliases emb_h)
  ushort* Q_T     = wsb + 33554432;    // [B,H,240,1024]
  ushort* Kh_T    = wsb + 49283072;    // [B,H,240,1024]
  ushort* Vh      = wsb + 65011712;    // [B,H,1024,256]
  ushort* wts     = wsb + 81788928;    // 716800: Wk_b|Wv_b|Wq_bd|Wo_b
  ushort* Wk_b  = wts;
  ushort* Wv_b  = wts + 61440;
  ushort* Wq_bd = wts + 122880;
  ushort* Wo_b  = wts + 368640;
  float*  stats = (float*)(wsb + 82505728);   // [64][4][2] fp32

  const float alpha_s = 1.0f / sqrtf(960.0f);

  conv_inputs<<<dim3(4096), 256, 0, stream>>>(emb_all, emb[0], emb[1], emb[2], emb[3],
                                              heads_b, emb_h);
  conv_weights<<<dim3(2800), 256, 0, stream>>>(Wk, Wv, Wq[0], Wq[1], Wq[2], Wq[3],
                                               Wo[0], Wo[1], Wo[2], Wo[3], wts);

  // merged K/V/Q projections
  mfma_proj<<<dim3(3072), 256, 0, stream>>>(heads_b, emb_h, Wk_b, Wv_b, Wq_bd,
                                            Kh_T, Vh, Q_T);

  // fused scores, split-K x2
  mfma_abT<<<dim3(4, 64, 2), 256, 0, stream>>>(
      Q_T, 1024, 240L * 1024, 512,
      Kh_T, 1024, 240L * 1024, 512,
      sc0, 240, (long)SC_, 64L * SC_,
      240, 240, 240, 512, alpha_s, 0, 2);

  // InstanceNorm stats + softmax apply (summing partials) -> bf16 probs
  in_stats<<<dim3(64, 4), 256, 0, stream>>>(sc0, sc1, stats);
  sm_apply<<<dim3(60, 64), 256, 0, stream>>>(sc0, sc1, stats, P_b);

  // fused ctx
  mfma_ctx<<<dim3(16, H_, B_), 256, 0, stream>>>(Vh, P_b, ctx2);

  // grouped out-proj
  mfma_oproj<<<dim3(1024), 256, 0, stream>>>(ctx2, Wo_b, out);
}